// Round 10
// baseline (699.097 us; speedup 1.0000x reference)
//
#include <hip/hip_runtime.h>
#include <hip/hip_bf16.h>
#include <cstddef>

#define N_NODES 65536
#define N_EDGES 524288
#define S_GRAPH 256
#define BN_EPS 1e-5f
#define THRE 0.7f

typedef __hip_bfloat16 bf16;
typedef unsigned int uint32;
typedef unsigned char uchar;
typedef unsigned short ushort16;
typedef __attribute__((ext_vector_type(8))) short short8;
typedef __attribute__((ext_vector_type(4))) float f32x4;

__device__ __forceinline__ float blo(uint32 u) { return __uint_as_float(u << 16); }
__device__ __forceinline__ float bhi(uint32 u) { return __uint_as_float(u & 0xffff0000u); }

__device__ __forceinline__ uint32 packbf(float a, float b)
{
    bf16 ha = __float2bfloat16(a), hb = __float2bfloat16(b);
    unsigned short ua, ub;
    __builtin_memcpy(&ua, &ha, 2); __builtin_memcpy(&ub, &hb, 2);
    return (uint32)ua | ((uint32)ub << 16);
}

// fast tanh: 1 - 2/(e^{2x}+1); |err| ~1e-6, far below bf16 rounding (2^-9)
__device__ __forceinline__ float ftanh(float x)
{
    float e = __builtin_amdgcn_exp2f(x * 2.8853900817779268f);  // 2*log2(e)
    return 1.0f - 2.0f * __builtin_amdgcn_rcpf(e + 1.0f);
}

// ---------------------------------------------------------------------------
// 1) Fused front-end, 2593 blocks (r7 topology: latency-bound MLP overlaps
//    transaction-bound hist):
//    [0..511] node MLP -> bf16 h0 + BN1 stats; [512..2559] edge histogram
//    (packed 32-bit atomic: hi8=count, lo24=wsum 2^-18 fix; old hi8 = rank);
//    [2560..2591] dense col sums; [2592] W1 fp32->bf16 pack
// ---------------------------------------------------------------------------
__global__ __launch_bounds__(256) void k_mlp_hist(
    const float* __restrict__ x, const float* __restrict__ wv,
    const float* __restrict__ bv, const float* __restrict__ wc,
    const float* __restrict__ bc, const int* __restrict__ nconp,
    uint32* __restrict__ h0u, float* __restrict__ stats,
    const int* __restrict__ dst, const float* __restrict__ ew,
    uint32* __restrict__ pk32, uchar* __restrict__ rank,
    const float* __restrict__ scen, float* __restrict__ fcol,
    const float* __restrict__ w1f, uint32* __restrict__ w1bk)
{
    int t = threadIdx.x;
    int b = blockIdx.x;
    if (b >= 512) {
        if (b < 2560) {                           // ---- histogram path ----
            int e = (b - 512) * 256 + t;
            int d = dst[e];
            uint32 wfix = __float2uint_rn(ew[e] * 262144.0f);   // 2^18
            uint32 old = atomicAdd(&pk32[d], (1u << 24) | wfix);
            rank[e] = (uchar)(old >> 24);
        } else if (b < 2592) {                    // ---- dense col sums ----
            int r0 = (b - 2560) * 8;
            float s = 0.f;
            for (int r = r0; r < r0 + 8; r++)
                s += (scen[r * 256 + t] >= THRE) ? 1.0f : 0.0f;
            atomicAdd(&fcol[t], s);
        } else {                                  // ---- W1 -> bf16 pack ----
            const float4* w4 = (const float4*)w1f;
            uint2* wo = (uint2*)w1bk;
            #pragma unroll
            for (int it = 0; it < 16; it++) {
                int fi = it * 256 + t;            // 4096 float4
                float4 w = w4[fi];
                wo[fi] = make_uint2(packbf(w.x, w.y), packbf(w.z, w.w));
            }
        }
        return;
    }
    // ---- node MLP path: block handles 128 nodes ----
    __shared__ float xs[128 * 6];
    __shared__ float sh[256];
    int n0 = b * 128;
    if (t < 192) ((float4*)xs)[t] = ((const float4*)(x + (size_t)n0 * 6))[t];
    __syncthreads();

    int nc = *nconp;
    int lane = t & 63, wave = t >> 6;
    int j0 = 2 * lane;
    const float2* wv2 = (const float2*)wv;
    float2 wa0 = wv2[j0 * 3], wa1 = wv2[j0 * 3 + 1], wa2 = wv2[j0 * 3 + 2];
    float2 wb0 = wv2[j0 * 3 + 3], wb1 = wv2[j0 * 3 + 4], wb2 = wv2[j0 * 3 + 5];
    float wc0 = wc[j0], wc1 = wc[j0 + 1], bc0 = bc[j0], bc1 = bc[j0 + 1];
    float bv0 = bv[j0], bv1 = bv[j0 + 1];

    float s0 = 0.f, ss0 = 0.f, s1 = 0.f, ss1 = 0.f;
    #pragma unroll 4
    for (int m = 0; m < 32; m++) {
        int ln = wave * 32 + m;                   // local node, wave-uniform
        int n = n0 + ln;
        const float* xr = &xs[ln * 6];
        float a0, a1;
        if (n < nc) {
            float xv = xr[0];
            a0 = xv * wc0 + bc0; a1 = xv * wc1 + bc1;
        } else {
            float x0 = xr[0], x1 = xr[1], x2 = xr[2], x3 = xr[3], x4 = xr[4], x5 = xr[5];
            a0 = bv0 + x0 * wa0.x + x1 * wa0.y + x2 * wa1.x + x3 * wa1.y + x4 * wa2.x + x5 * wa2.y;
            a1 = bv1 + x0 * wb0.x + x1 * wb0.y + x2 * wb1.x + x3 * wb1.y + x4 * wb2.x + x5 * wb2.y;
        }
        uint32 pk = packbf(ftanh(a0), ftanh(a1));
        h0u[(size_t)n * 64 + lane] = pk;
        float v0 = blo(pk), v1 = bhi(pk);         // stats on rounded values
        s0 += v0; ss0 += v0 * v0; s1 += v1; ss1 += v1 * v1;
    }
    sh[t] = s0; __syncthreads();
    if (t < 64) atomicAdd(&stats[2 * t], sh[t] + sh[t + 64] + sh[t + 128] + sh[t + 192]);
    __syncthreads(); sh[t] = s1; __syncthreads();
    if (t < 64) atomicAdd(&stats[2 * t + 1], sh[t] + sh[t + 64] + sh[t + 128] + sh[t + 192]);
    __syncthreads(); sh[t] = ss0; __syncthreads();
    if (t < 64) atomicAdd(&stats[128 + 2 * t], sh[t] + sh[t + 64] + sh[t + 128] + sh[t + 192]);
    __syncthreads(); sh[t] = ss1; __syncthreads();
    if (t < 64) atomicAdd(&stats[128 + 2 * t + 1], sh[t] + sh[t + 64] + sh[t + 128] + sh[t + 192]);
}

// ---------------------------------------------------------------------------
// 2) Fused scan + gemm1 + fill, 3584 blocks:
//    [0..255]     scan of padded counts -> rowp; dinv; last block: boff,
//                 then sets scan-done flag (ctr[1])
//    [256..1279]  xw = BN1(h0) @ W1^T via MFMA bf16 (independent of scan)
//    [1280..3327] fill real edges (spin on ctr[1])
//    [3328..3583] fill pad slots [cnt,pcnt) with (n,0) (spin on ctr[1])
// ---------------------------------------------------------------------------
__global__ __launch_bounds__(256) void k_gemm1f(
    const uint32* __restrict__ h0u, const uint32* __restrict__ w1bk,
    const float* __restrict__ g1, const float* __restrict__ bb1,
    const float* __restrict__ stats, ushort16* __restrict__ xws,
    const int* __restrict__ src, const int* __restrict__ dst,
    const float* __restrict__ ew, float* __restrict__ deg,
    int* __restrict__ rowp, int* __restrict__ bsum, int* __restrict__ boff,
    const uchar* __restrict__ rank, const uint32* __restrict__ pk32,
    int2* __restrict__ epk, int* __restrict__ ctrs)
{
    int t = threadIdx.x;
    int blk = blockIdx.x;
    if (blk < 256) {                              // ---- scan phase ----
        __shared__ int sh[256];
        __shared__ int flag;
        int i = blk * 256 + t;
        uint32 pv = pk32[i];
        int cnt = (int)(pv >> 24);
        int pcnt = (cnt + 3) & ~3;
        deg[i] = rsqrtf((float)(pv & 0xFFFFFFu) * 3.814697265625e-6f + 1.0f);
        sh[t] = pcnt; __syncthreads();
        for (int o = 1; o < 256; o <<= 1) {
            int u = (t >= o) ? sh[t - o] : 0;
            __syncthreads();
            sh[t] += u;
            __syncthreads();
        }
        rowp[i] = sh[t] - pcnt;
        if (t == 255) atomicExch(&bsum[blk], sh[255]);
        __syncthreads();
        if (t == 0) {
            __threadfence();                      // wb: rowp/deg visible
            flag = (atomicAdd(&ctrs[0], 1) == 255) ? 1 : 0;
        }
        __syncthreads();
        if (flag) {
            __threadfence();
            int v = bsum[t];
            sh[t] = v; __syncthreads();
            for (int o = 1; o < 256; o <<= 1) {
                int u = (t >= o) ? sh[t - o] : 0;
                __syncthreads();
                sh[t] += u;
                __syncthreads();
            }
            boff[t] = sh[t] - v;
            __syncthreads();
            if (t == 0) {
                __threadfence();                  // wb: boff visible
                atomicExch(&ctrs[1], 1);          // scan-done flag
            }
        }
        return;
    }
    if (blk >= 1280) {                            // ---- fill paths ----
        if (t == 0) {
            while (atomicAdd(&ctrs[1], 0) == 0) __builtin_amdgcn_s_sleep(8);
        }
        __syncthreads();
        __threadfence();                          // acquire: inv stale lines
        if (blk < 3328) {                         // fill real edges
            int e = (blk - 1280) * 256 + t;
            int s = src[e], d = dst[e];
            int p = rowp[d] + boff[d >> 8] + (int)rank[e];
            float w = deg[s] * ew[e] * deg[d];
            epk[p] = make_int2(s, __float_as_int(w));
        } else {                                  // fill pads
            int n = (blk - 3328) * 256 + t;
            int st = rowp[n] + boff[n >> 8];
            int cnt = (int)(pk32[n] >> 24);
            int pcnt = (cnt + 3) & ~3;
            for (int q = cnt; q < pcnt; q++) epk[st + q] = make_int2(n, 0);
        }
        return;
    }
    // ---- MFMA gemm path: blocks 256..1279 ----
    __shared__ short hn_s[64 * 136];    // bf16 bits, row-major, stride 136 (2-way max)
    __shared__ short w_s[128 * 136];
    __shared__ float sc[128], sf[128];
    int row0 = (blk - 256) * 64;

    if (t < 128) {
        float mu  = stats[t] * (1.0f / N_NODES);
        float var = stats[128 + t] * (1.0f / N_NODES) - mu * mu;
        float rs  = rsqrtf(fmaxf(var, 0.f) + BN_EPS);
        float s   = rs * g1[t];
        sc[t] = s;
        sf[t] = bb1[t] - mu * s;
    }
    __syncthreads();

    const uint4* h4 = (const uint4*)(h0u + (size_t)row0 * 64);
    #pragma unroll
    for (int it = 0; it < 4; it++) {
        int slot = it * 256 + t;
        int r = slot >> 4, k0 = (slot & 15) * 8;
        uint4 u = h4[slot];
        uint32 ua[4] = {u.x, u.y, u.z, u.w};
        uint32 o[4];
        #pragma unroll
        for (int m = 0; m < 4; m++) {
            int k = k0 + 2 * m;
            o[m] = packbf(blo(ua[m]) * sc[k] + sf[k], bhi(ua[m]) * sc[k + 1] + sf[k + 1]);
        }
        *(uint4*)&hn_s[r * 136 + k0] = make_uint4(o[0], o[1], o[2], o[3]);
    }
    const uint4* wv4 = (const uint4*)w1bk;
    #pragma unroll
    for (int it = 0; it < 8; it++) {
        int s2 = it * 256 + t;              // 2048 uint4 (8 bf16 each)
        int c = s2 >> 4, k0 = (s2 & 15) * 8;
        *(uint4*)&w_s[c * 136 + k0] = wv4[s2];
    }
    __syncthreads();

    int lane = t & 63, wave = t >> 6;
    int m16 = lane & 15, kh = lane >> 4;
    int mbase = wave * 16;
    f32x4 acc[8] = {};
    #pragma unroll
    for (int ks = 0; ks < 4; ks++) {
        short8 a = *(const short8*)&hn_s[(mbase + m16) * 136 + ks * 32 + kh * 8];
        #pragma unroll
        for (int ct = 0; ct < 8; ct++) {
            short8 bfr = *(const short8*)&w_s[(ct * 16 + m16) * 136 + ks * 32 + kh * 8];
            acc[ct] = __builtin_amdgcn_mfma_f32_16x16x32_bf16(a, bfr, acc[ct], 0, 0, 0);
        }
    }
    #pragma unroll
    for (int ct = 0; ct < 8; ct++) {
        int col = ct * 16 + m16;
        #pragma unroll
        for (int r = 0; r < 4; r++) {
            int row = mbase + kh * 4 + r;
            bf16 hv = __float2bfloat16(acc[ct][r]);
            unsigned short us; __builtin_memcpy(&us, &hv, 2);
            xws[(size_t)(row0 + row) * 128 + col] = us;
        }
    }
}

// ---------------------------------------------------------------------------
// 3) CSR gather, remainder-free (rows padded to 4)
// ---------------------------------------------------------------------------
__global__ void k_gather(const int* __restrict__ rowp, const int* __restrict__ boff,
                         const uint32* __restrict__ pk32, const int2* __restrict__ epk,
                         const uint32* __restrict__ xwu, const float* __restrict__ dinv,
                         const float2* __restrict__ b1c2, uint32* __restrict__ aggu)
{
    int t = threadIdx.x;
    int lane = t & 63;
    int n = blockIdx.x * 4 + (t >> 6);
    int st = rowp[n] + boff[n >> 8];
    int pcnt = (((int)(pk32[n] >> 24)) + 3) & ~3;
    float di = dinv[n];
    float d2 = di * di;
    uint32 u0 = xwu[(size_t)n * 64 + lane];
    float2 bb = b1c2[lane];
    float ax = d2 * blo(u0) + bb.x;
    float ay = d2 * bhi(u0) + bb.y;
    int en = st + pcnt;
    for (int p = st; p < en; p += 4) {
        int2 q0 = epk[p], q1 = epk[p + 1], q2 = epk[p + 2], q3 = epk[p + 3];
        uint32 v0 = xwu[(size_t)q0.x * 64 + lane];
        uint32 v1 = xwu[(size_t)q1.x * 64 + lane];
        uint32 v2 = xwu[(size_t)q2.x * 64 + lane];
        uint32 v3 = xwu[(size_t)q3.x * 64 + lane];
        float w0 = __int_as_float(q0.y), w1 = __int_as_float(q1.y);
        float w2 = __int_as_float(q2.y), w3 = __int_as_float(q3.y);
        ax += w0 * blo(v0) + w1 * blo(v1) + w2 * blo(v2) + w3 * blo(v3);
        ay += w0 * bhi(v0) + w1 * bhi(v1) + w2 * bhi(v2) + w3 * bhi(v3);
    }
    aggu[(size_t)n * 64 + lane] = packbf(ax, ay);
}

// ---------------------------------------------------------------------------
// device-wide barrier for 256 co-resident blocks (release wb / acquire inv)
// ---------------------------------------------------------------------------
__device__ __forceinline__ void gbar(int* ctr, int nb)
{
    __syncthreads();
    if (threadIdx.x == 0) {
        __threadfence();                  // release: writeback L2
        atomicAdd(ctr, 1);
        while (atomicAdd(ctr, 0) < nb) __builtin_amdgcn_s_sleep(4);
    }
    __syncthreads();
    __threadfence();                      // acquire: invalidate stale lines
}

// ---------------------------------------------------------------------------
// 4) Mega-tail: colstats -> pool -> gemm2 -> dgcn1(+BN3 stats) -> gemm3 ->
//    dgcn2(+mean). 256 blocks x 256 threads, all co-resident; 5 barriers.
// ---------------------------------------------------------------------------
__global__ __launch_bounds__(256) void k_tail(
    const uint32* __restrict__ aggu, float* __restrict__ stats2,
    const float* __restrict__ g2, const float* __restrict__ bb2,
    float* __restrict__ pooled, const float* __restrict__ w2,
    float* __restrict__ z1, const float* __restrict__ scen,
    const float* __restrict__ fcol, const float* __restrict__ b2c,
    float* __restrict__ y1, float* __restrict__ stats3r,
    const float* __restrict__ g3, const float* __restrict__ bb3,
    const float* __restrict__ w3, float* __restrict__ z2,
    const float* __restrict__ b3c, float* __restrict__ out,
    float* __restrict__ meanr, int* __restrict__ ctrs)
{
    __shared__ float shA[256];
    __shared__ float sc[128], sf[128];
    __shared__ int flag;
    int t = threadIdx.x, blk = blockIdx.x;

    // ---- P0: column stats over bf16 agg -> stats2 ----
    {
        float s0 = 0.f, ss0 = 0.f, s1 = 0.f, ss1 = 0.f;
        for (int idx = blk * 256 + t; idx < N_NODES * 64; idx += 256 * 256) {
            uint32 u = aggu[idx];
            float a = blo(u), b = bhi(u);
            s0 += a; ss0 += a * a; s1 += b; ss1 += b * b;
        }
        shA[t] = s0; __syncthreads();
        if (t < 64) atomicAdd(&stats2[2 * t], shA[t] + shA[t + 64] + shA[t + 128] + shA[t + 192]);
        __syncthreads(); shA[t] = s1; __syncthreads();
        if (t < 64) atomicAdd(&stats2[2 * t + 1], shA[t] + shA[t + 64] + shA[t + 128] + shA[t + 192]);
        __syncthreads(); shA[t] = ss0; __syncthreads();
        if (t < 64) atomicAdd(&stats2[128 + 2 * t], shA[t] + shA[t + 64] + shA[t + 128] + shA[t + 192]);
        __syncthreads(); shA[t] = ss1; __syncthreads();
        if (t < 64) atomicAdd(&stats2[128 + 2 * t + 1], shA[t] + shA[t + 64] + shA[t + 128] + shA[t + 192]);
    }
    gbar(&ctrs[2], 256);

    // ---- P1: mean-pool of tanh(BN2(agg)) for graph g = blk ----
    {
        if (t < 128) {
            float mu  = stats2[t] * (1.0f / N_NODES);
            float var = stats2[128 + t] * (1.0f / N_NODES) - mu * mu;
            float rs  = rsqrtf(fmaxf(var, 0.f) + BN_EPS);
            float s   = rs * g2[t];
            sc[t] = s;
            sf[t] = bb2[t] - mu * s;
        }
        __syncthreads();
        int c = t & 63, grp = t >> 6;
        float c0s = sc[2 * c], c0f = sf[2 * c], c1s = sc[2 * c + 1], c1f = sf[2 * c + 1];
        const uint32* base = aggu + (size_t)blk * 256 * 64;
        float s0 = 0.f, s1 = 0.f;
        for (int r = grp * 64; r < grp * 64 + 64; r++) {
            uint32 u = base[r * 64 + c];
            s0 += ftanh(blo(u) * c0s + c0f);
            s1 += ftanh(bhi(u) * c1s + c1f);
        }
        shA[t] = s0; __syncthreads();
        if (t < 64) pooled[blk * 128 + 2 * t] = (shA[t] + shA[t + 64] + shA[t + 128] + shA[t + 192]) * (1.0f / 256.0f);
        __syncthreads(); shA[t] = s1; __syncthreads();
        if (t < 64) pooled[blk * 128 + 2 * t + 1] = (shA[t] + shA[t + 64] + shA[t + 128] + shA[t + 192]) * (1.0f / 256.0f);
    }
    gbar(&ctrs[3], 256);

    // ---- P2: z1 = pooled @ W2^T, row i = blk ----
    {
        if (t < 128) shA[t] = pooled[blk * 128 + t];
        __syncthreads();
        float acc = 0.f;
        const float* wr = w2 + t * 128;
        for (int k = 0; k < 128; k++) acc += shA[k] * wr[k];
        z1[blk * 256 + t] = acc;
    }
    gbar(&ctrs[4], 256);

    // ---- P3: y1 = dense GCN(z1) + BN3 stats (8-way replicas) ----
    {
        __syncthreads();
        float a = (scen[t * 256 + blk] >= THRE) ? 1.0f : 0.0f;
        if (t == blk) a += 1.0f;
        shA[t] = a * rsqrtf(fcol[t] + 1.0f);
        __syncthreads();
        float acc = 0.f;
        for (int k = 0; k < 256; k++) acc += shA[k] * z1[k * 256 + t];
        float v = rsqrtf(fcol[blk] + 1.0f) * acc + b2c[t];
        y1[blk * 256 + t] = v;
        float* s3 = stats3r + (blk & 7) * 512;
        atomicAdd(&s3[t], v);
        atomicAdd(&s3[256 + t], v * v);
    }
    gbar(&ctrs[5], 256);

    // ---- P4: z2 = tanh(BN3(y1)) @ W3^T, row i = blk ----
    {
        float s = 0.f, ss = 0.f;
        #pragma unroll
        for (int r = 0; r < 8; r++) {
            s  += stats3r[r * 512 + t];
            ss += stats3r[r * 512 + 256 + t];
        }
        float mu  = s * (1.0f / 256.0f);
        float var = ss * (1.0f / 256.0f) - mu * mu;
        float rs  = rsqrtf(fmaxf(var, 0.f) + BN_EPS);
        float scj = rs * g3[t];
        float sfj = bb3[t] - mu * scj;
        shA[t] = ftanh(y1[blk * 256 + t] * scj + sfj);
        __syncthreads();
        if (t < 128) {
            float acc = 0.f;
            const float* wr = w3 + t * 256;
            for (int k = 0; k < 256; k++) acc += shA[k] * wr[k];
            z2[blk * 128 + t] = acc;
        }
    }
    gbar(&ctrs[6], 256);

    // ---- P5: feat = tanh(dense GCN(z2)) -> out; mean via replicas ----
    {
        __syncthreads();
        float a = (scen[t * 256 + blk] >= THRE) ? 1.0f : 0.0f;
        if (t == blk) a += 1.0f;
        shA[t] = a * rsqrtf(fcol[t] + 1.0f);
        __syncthreads();
        if (t < 128) {
            float acc = 0.f;
            for (int k = 0; k < 256; k++) acc += shA[k] * z2[k * 128 + t];
            float v = ftanh(rsqrtf(fcol[blk] + 1.0f) * acc + b3c[t]);
            out[blk * 128 + t] = v;
            atomicAdd(&meanr[(blk & 7) * 128 + t], v);
        }
        __syncthreads();
        if (t == 0) {
            __threadfence();
            flag = (atomicAdd(&ctrs[7], 1) == 255) ? 1 : 0;
        }
        __syncthreads();
        if (flag) {
            __threadfence();
            if (t < 128) {
                float s = 0.f;
                #pragma unroll
                for (int r = 0; r < 8; r++) s += meanr[r * 128 + t];
                out[S_GRAPH * 128 + t] = s * (1.0f / 256.0f);
            }
        }
    }
}

// ---------------------------------------------------------------------------
extern "C" void kernel_launch(void* const* d_in, const int* in_sizes, int n_in,
                              void* d_out, int out_size, void* d_ws, size_t ws_size,
                              hipStream_t stream)
{
    const float* x        = (const float*)d_in[0];
    const float* edge_attr= (const float*)d_in[1];
    const float* scen     = (const float*)d_in[2];
    const float* wv       = (const float*)d_in[3];
    const float* bv       = (const float*)d_in[4];
    const float* wc       = (const float*)d_in[5];
    const float* bc       = (const float*)d_in[6];
    const float* w1       = (const float*)d_in[7];
    const float* b1c      = (const float*)d_in[8];
    const float* w2       = (const float*)d_in[9];
    const float* b2c      = (const float*)d_in[10];
    const float* w3       = (const float*)d_in[11];
    const float* b3c      = (const float*)d_in[12];
    const float* g1       = (const float*)d_in[13];
    const float* bb1      = (const float*)d_in[14];
    const float* g2       = (const float*)d_in[15];
    const float* bb2      = (const float*)d_in[16];
    const float* g3       = (const float*)d_in[17];
    const float* bb3      = (const float*)d_in[18];
    const int*  ei        = (const int*)d_in[20];
    const int*  nconp     = (const int*)d_in[22];
    const int*  src = ei;
    const int*  dst = ei + N_EDGES;

    float* wsf = (float*)d_ws;
    uint32*   h0u  = (uint32*)wsf;            // 16.7MB, dead after gemm1
    uint32*   aggu = (uint32*)wsf;            // alias
    uint32*   xwu  = (uint32*)(wsf + 4194304);// 16.7MB
    // zero-init block: pk32, stats, replicas, fcol, meanr, counters
    float* zb      = wsf + 8388608;
    uint32* pk32   = (uint32*)zb;             // 65536
    float* stats1  = zb + 65536;              // 512
    float* stats2  = stats1 + 512;            // 512
    float* stats3r = stats2 + 512;            // 4096
    float* fcol    = stats3r + 4096;          // 256
    float* meanr   = fcol + 256;              // 1024
    int*   ctrs    = (int*)(meanr + 1024);    // 8 counters
    const int ZN   = 65536 + 512 * 2 + 4096 + 256 + 1024 + 8;
    float* deg     = zb + ZN;                 // 65536 (dinv)
    int*   rowp    = (int*)(deg + 65536);     // 65536 (padded partial scan)
    int*   bsum    = rowp + 65536;            // 256
    int*   boff    = bsum + 256;              // 256
    uchar* rank    = (uchar*)(boff + 256);    // 524288 bytes
    int2*  epk     = (int2*)((float*)rank + 131072);  // up to 720896 int2
    uint32* w1bk   = (uint32*)(epk + 720896); // 8192 (32KB bf16 W1)
    float* pooled  = (float*)(w1bk + 8192);   // 32768
    float* z1      = pooled + 32768;          // 65536
    float* y1      = z1 + 65536;              // 65536
    float* z2      = y1 + 65536;              // 32768

    float* out = (float*)d_out;

    hipMemsetAsync(zb, 0, ZN * sizeof(float), stream);

    k_mlp_hist<<<2593, 256, 0, stream>>>(x, wv, bv, wc, bc, nconp, h0u, stats1,
                                         dst, edge_attr, pk32, rank,
                                         scen, fcol, w1, w1bk);
    k_gemm1f<<<3584, 256, 0, stream>>>(h0u, w1bk, g1, bb1, stats1, (ushort16*)xwu,
                                       src, dst, edge_attr, deg, rowp, bsum, boff,
                                       rank, pk32, epk, ctrs);
    k_gather<<<N_NODES / 4, 256, 0, stream>>>(rowp, boff, pk32, epk, xwu, deg,
                                              (const float2*)b1c, aggu);
    k_tail<<<256, 256, 0, stream>>>(aggu, stats2, g2, bb2, pooled, w2, z1,
                                    scen, fcol, b2c, y1, stats3r, g3, bb3, w3,
                                    z2, b3c, out, meanr, ctrs);
}

// Round 11
// 421.639 us; speedup vs baseline: 1.6580x; 1.6580x over previous
//
#include <hip/hip_runtime.h>
#include <hip/hip_bf16.h>
#include <cstddef>

#define N_NODES 65536
#define N_EDGES 524288
#define S_GRAPH 256
#define BN_EPS 1e-5f
#define THRE 0.7f

typedef __hip_bfloat16 bf16;
typedef unsigned int uint32;
typedef unsigned char uchar;
typedef unsigned short ushort16;
typedef __attribute__((ext_vector_type(8))) short short8;
typedef __attribute__((ext_vector_type(4))) float f32x4;

__device__ __forceinline__ float blo(uint32 u) { return __uint_as_float(u << 16); }
__device__ __forceinline__ float bhi(uint32 u) { return __uint_as_float(u & 0xffff0000u); }

__device__ __forceinline__ uint32 packbf(float a, float b)
{
    bf16 ha = __float2bfloat16(a), hb = __float2bfloat16(b);
    unsigned short ua, ub;
    __builtin_memcpy(&ua, &ha, 2); __builtin_memcpy(&ub, &hb, 2);
    return (uint32)ua | ((uint32)ub << 16);
}

// fast tanh: 1 - 2/(e^{2x}+1); |err| ~1e-6, far below bf16 rounding (2^-9)
__device__ __forceinline__ float ftanh(float x)
{
    float e = __builtin_amdgcn_exp2f(x * 2.8853900817779268f);  // 2*log2(e)
    return 1.0f - 2.0f * __builtin_amdgcn_rcpf(e + 1.0f);
}

// ---------------------------------------------------------------------------
// 1) Fused front-end, 2593 blocks (latency-bound MLP overlaps transaction-
//    bound hist; both LDS-light):
//    [0..511] node MLP -> bf16 h0 + BN1 stats; [512..2559] edge histogram
//    (packed 32-bit atomic: hi8=count, lo24=wsum 2^-18 fix; old hi8 = rank);
//    [2560..2591] dense col sums; [2592] W1 fp32->bf16 pack
// ---------------------------------------------------------------------------
__global__ __launch_bounds__(256) void k_mlp_hist(
    const float* __restrict__ x, const float* __restrict__ wv,
    const float* __restrict__ bv, const float* __restrict__ wc,
    const float* __restrict__ bc, const int* __restrict__ nconp,
    uint32* __restrict__ h0u, float* __restrict__ stats,
    const int* __restrict__ dst, const float* __restrict__ ew,
    uint32* __restrict__ pk32, uchar* __restrict__ rank,
    const float* __restrict__ scen, float* __restrict__ fcol,
    const float* __restrict__ w1f, uint32* __restrict__ w1bk)
{
    int t = threadIdx.x;
    int b = blockIdx.x;
    if (b >= 512) {
        if (b < 2560) {                           // ---- histogram path ----
            int e = (b - 512) * 256 + t;
            int d = dst[e];
            uint32 wfix = __float2uint_rn(ew[e] * 262144.0f);   // 2^18
            uint32 old = atomicAdd(&pk32[d], (1u << 24) | wfix);
            rank[e] = (uchar)(old >> 24);
        } else if (b < 2592) {                    // ---- dense col sums ----
            int r0 = (b - 2560) * 8;
            float s = 0.f;
            for (int r = r0; r < r0 + 8; r++)
                s += (scen[r * 256 + t] >= THRE) ? 1.0f : 0.0f;
            atomicAdd(&fcol[t], s);
        } else {                                  // ---- W1 -> bf16 pack ----
            const float4* w4 = (const float4*)w1f;
            uint2* wo = (uint2*)w1bk;
            #pragma unroll
            for (int it = 0; it < 16; it++) {
                int fi = it * 256 + t;            // 4096 float4
                float4 w = w4[fi];
                wo[fi] = make_uint2(packbf(w.x, w.y), packbf(w.z, w.w));
            }
        }
        return;
    }
    // ---- node MLP path: block handles 128 nodes ----
    __shared__ float xs[128 * 6];
    __shared__ float sh[256];
    int n0 = b * 128;
    if (t < 192) ((float4*)xs)[t] = ((const float4*)(x + (size_t)n0 * 6))[t];
    __syncthreads();

    int nc = *nconp;
    int lane = t & 63, wave = t >> 6;
    int j0 = 2 * lane;
    const float2* wv2 = (const float2*)wv;
    float2 wa0 = wv2[j0 * 3], wa1 = wv2[j0 * 3 + 1], wa2 = wv2[j0 * 3 + 2];
    float2 wb0 = wv2[j0 * 3 + 3], wb1 = wv2[j0 * 3 + 4], wb2 = wv2[j0 * 3 + 5];
    float wc0 = wc[j0], wc1 = wc[j0 + 1], bc0 = bc[j0], bc1 = bc[j0 + 1];
    float bv0 = bv[j0], bv1 = bv[j0 + 1];

    float s0 = 0.f, ss0 = 0.f, s1 = 0.f, ss1 = 0.f;
    #pragma unroll 4
    for (int m = 0; m < 32; m++) {
        int ln = wave * 32 + m;                   // local node, wave-uniform
        int n = n0 + ln;
        const float* xr = &xs[ln * 6];
        float a0, a1;
        if (n < nc) {
            float xv = xr[0];
            a0 = xv * wc0 + bc0; a1 = xv * wc1 + bc1;
        } else {
            float x0 = xr[0], x1 = xr[1], x2 = xr[2], x3 = xr[3], x4 = xr[4], x5 = xr[5];
            a0 = bv0 + x0 * wa0.x + x1 * wa0.y + x2 * wa1.x + x3 * wa1.y + x4 * wa2.x + x5 * wa2.y;
            a1 = bv1 + x0 * wb0.x + x1 * wb0.y + x2 * wb1.x + x3 * wb1.y + x4 * wb2.x + x5 * wb2.y;
        }
        uint32 pk = packbf(ftanh(a0), ftanh(a1));
        h0u[(size_t)n * 64 + lane] = pk;
        float v0 = blo(pk), v1 = bhi(pk);         // stats on rounded values
        s0 += v0; ss0 += v0 * v0; s1 += v1; ss1 += v1 * v1;
    }
    sh[t] = s0; __syncthreads();
    if (t < 64) atomicAdd(&stats[2 * t], sh[t] + sh[t + 64] + sh[t + 128] + sh[t + 192]);
    __syncthreads(); sh[t] = s1; __syncthreads();
    if (t < 64) atomicAdd(&stats[2 * t + 1], sh[t] + sh[t + 64] + sh[t + 128] + sh[t + 192]);
    __syncthreads(); sh[t] = ss0; __syncthreads();
    if (t < 64) atomicAdd(&stats[128 + 2 * t], sh[t] + sh[t + 64] + sh[t + 128] + sh[t + 192]);
    __syncthreads(); sh[t] = ss1; __syncthreads();
    if (t < 64) atomicAdd(&stats[128 + 2 * t + 1], sh[t] + sh[t + 64] + sh[t + 128] + sh[t + 192]);
}

// ---------------------------------------------------------------------------
// 2) Scan of PADDED counts ((cnt+3)&~3) -> rowp/bsum; dinv finalize; last-
//    finishing block performs the 256-entry top-level scan (boff).
// ---------------------------------------------------------------------------
__global__ void k_scan(const uint32* __restrict__ pk32, int* __restrict__ rowp,
                       int* __restrict__ bsum, int* __restrict__ boff,
                       float* __restrict__ deg, int* __restrict__ ctr)
{
    __shared__ int sh[256];
    __shared__ int flag;
    int b = blockIdx.x, t = threadIdx.x;
    int i = b * 256 + t;
    uint32 pv = pk32[i];
    int cnt = (int)(pv >> 24);
    int pcnt = (cnt + 3) & ~3;
    deg[i] = rsqrtf((float)(pv & 0xFFFFFFu) * 3.814697265625e-6f + 1.0f);  // 2^-18
    sh[t] = pcnt; __syncthreads();
    for (int o = 1; o < 256; o <<= 1) {
        int u = (t >= o) ? sh[t - o] : 0;
        __syncthreads();
        sh[t] += u;
        __syncthreads();
    }
    rowp[i] = sh[t] - pcnt;
    if (t == 255) atomicExch(&bsum[b], sh[255]);   // coherent-point write
    __syncthreads();
    if (t == 0) {
        __threadfence();
        flag = (atomicAdd(ctr, 1) == 255) ? 1 : 0;
    }
    __syncthreads();
    if (flag) {
        __threadfence();
        int v = bsum[t];
        sh[t] = v; __syncthreads();
        for (int o = 1; o < 256; o <<= 1) {
            int u = (t >= o) ? sh[t - o] : 0;
            __syncthreads();
            sh[t] += u;
            __syncthreads();
        }
        boff[t] = sh[t] - v;
    }
}

// ---------------------------------------------------------------------------
// 3) Fused: [0..1023]    xw = BN1(h0) @ W1^T via MFMA bf16
//           [1024..3071] fill real edges at rowp+boff+rank (atomic-free)
//           [3072..3327] fill pad slots [cnt,pcnt) with (n, w=0)
//    (fill paths share the kernel's LDS footprint but proved fine in r9)
// ---------------------------------------------------------------------------
__global__ __launch_bounds__(256) void k_gemm1f(
    const uint32* __restrict__ h0u, const uint32* __restrict__ w1bk,
    const float* __restrict__ g1, const float* __restrict__ bb1,
    const float* __restrict__ stats, ushort16* __restrict__ xws,
    const int* __restrict__ src, const int* __restrict__ dst,
    const float* __restrict__ ew, const float* __restrict__ dinv,
    const int* __restrict__ rowp, const int* __restrict__ boff,
    const uchar* __restrict__ rank, const uint32* __restrict__ pk32,
    int2* __restrict__ epk)
{
    int t = threadIdx.x;
    int blk = blockIdx.x;
    if (blk >= 1024) {
        if (blk < 3072) {                         // ---- fill real edges ----
            int e = (blk - 1024) * 256 + t;
            int s = src[e], d = dst[e];
            int p = rowp[d] + boff[d >> 8] + (int)rank[e];
            float w = dinv[s] * ew[e] * dinv[d];
            epk[p] = make_int2(s, __float_as_int(w));
        } else {                                  // ---- fill pads ----
            int n = (blk - 3072) * 256 + t;
            int st = rowp[n] + boff[n >> 8];
            int cnt = (int)(pk32[n] >> 24);
            int pcnt = (cnt + 3) & ~3;
            for (int q = cnt; q < pcnt; q++) epk[st + q] = make_int2(n, 0);
        }
        return;
    }
    __shared__ short hn_s[64 * 136];    // bf16 bits, row-major, stride 136 (2-way max)
    __shared__ short w_s[128 * 136];
    __shared__ float sc[128], sf[128];
    int row0 = blk * 64;

    if (t < 128) {
        float mu  = stats[t] * (1.0f / N_NODES);
        float var = stats[128 + t] * (1.0f / N_NODES) - mu * mu;
        float rs  = rsqrtf(fmaxf(var, 0.f) + BN_EPS);
        float s   = rs * g1[t];
        sc[t] = s;
        sf[t] = bb1[t] - mu * s;
    }
    __syncthreads();

    const uint4* h4 = (const uint4*)(h0u + (size_t)row0 * 64);
    #pragma unroll
    for (int it = 0; it < 4; it++) {
        int slot = it * 256 + t;
        int r = slot >> 4, k0 = (slot & 15) * 8;
        uint4 u = h4[slot];
        uint32 ua[4] = {u.x, u.y, u.z, u.w};
        uint32 o[4];
        #pragma unroll
        for (int m = 0; m < 4; m++) {
            int k = k0 + 2 * m;
            o[m] = packbf(blo(ua[m]) * sc[k] + sf[k], bhi(ua[m]) * sc[k + 1] + sf[k + 1]);
        }
        *(uint4*)&hn_s[r * 136 + k0] = make_uint4(o[0], o[1], o[2], o[3]);
    }
    const uint4* wv4 = (const uint4*)w1bk;
    #pragma unroll
    for (int it = 0; it < 8; it++) {
        int s2 = it * 256 + t;              // 2048 uint4 (8 bf16 each)
        int c = s2 >> 4, k0 = (s2 & 15) * 8;
        *(uint4*)&w_s[c * 136 + k0] = wv4[s2];
    }
    __syncthreads();

    int lane = t & 63, wave = t >> 6;
    int m16 = lane & 15, kh = lane >> 4;
    int mbase = wave * 16;
    f32x4 acc[8] = {};
    #pragma unroll
    for (int ks = 0; ks < 4; ks++) {
        short8 a = *(const short8*)&hn_s[(mbase + m16) * 136 + ks * 32 + kh * 8];
        #pragma unroll
        for (int ct = 0; ct < 8; ct++) {
            short8 bfr = *(const short8*)&w_s[(ct * 16 + m16) * 136 + ks * 32 + kh * 8];
            acc[ct] = __builtin_amdgcn_mfma_f32_16x16x32_bf16(a, bfr, acc[ct], 0, 0, 0);
        }
    }
    #pragma unroll
    for (int ct = 0; ct < 8; ct++) {
        int col = ct * 16 + m16;
        #pragma unroll
        for (int r = 0; r < 4; r++) {
            int row = mbase + kh * 4 + r;
            bf16 hv = __float2bfloat16(acc[ct][r]);
            unsigned short us; __builtin_memcpy(&us, &hv, 2);
            xws[(size_t)(row0 + row) * 128 + col] = us;
        }
    }
}

// ---------------------------------------------------------------------------
// 4) CSR gather, remainder-free (rows padded to 4)
// ---------------------------------------------------------------------------
__global__ void k_gather(const int* __restrict__ rowp, const int* __restrict__ boff,
                         const uint32* __restrict__ pk32, const int2* __restrict__ epk,
                         const uint32* __restrict__ xwu, const float* __restrict__ dinv,
                         const float2* __restrict__ b1c2, uint32* __restrict__ aggu)
{
    int t = threadIdx.x;
    int lane = t & 63;
    int n = blockIdx.x * 4 + (t >> 6);
    int st = rowp[n] + boff[n >> 8];
    int pcnt = (((int)(pk32[n] >> 24)) + 3) & ~3;
    float di = dinv[n];
    float d2 = di * di;
    uint32 u0 = xwu[(size_t)n * 64 + lane];
    float2 bb = b1c2[lane];
    float ax = d2 * blo(u0) + bb.x;
    float ay = d2 * bhi(u0) + bb.y;
    int en = st + pcnt;
    for (int p = st; p < en; p += 4) {
        int2 q0 = epk[p], q1 = epk[p + 1], q2 = epk[p + 2], q3 = epk[p + 3];
        uint32 v0 = xwu[(size_t)q0.x * 64 + lane];
        uint32 v1 = xwu[(size_t)q1.x * 64 + lane];
        uint32 v2 = xwu[(size_t)q2.x * 64 + lane];
        uint32 v3 = xwu[(size_t)q3.x * 64 + lane];
        float w0 = __int_as_float(q0.y), w1 = __int_as_float(q1.y);
        float w2 = __int_as_float(q2.y), w3 = __int_as_float(q3.y);
        ax += w0 * blo(v0) + w1 * blo(v1) + w2 * blo(v2) + w3 * blo(v3);
        ay += w0 * bhi(v0) + w1 * bhi(v1) + w2 * bhi(v2) + w3 * bhi(v3);
    }
    aggu[(size_t)n * 64 + lane] = packbf(ax, ay);
}

// ---------------------------------------------------------------------------
// device-wide barrier for 256 co-resident blocks (release wb / acquire inv)
// ---------------------------------------------------------------------------
__device__ __forceinline__ void gbar(int* ctr, int nb)
{
    __syncthreads();
    if (threadIdx.x == 0) {
        __threadfence();                  // release: writeback L2
        atomicAdd(ctr, 1);
        while (atomicAdd(ctr, 0) < nb) __builtin_amdgcn_s_sleep(4);
    }
    __syncthreads();
    __threadfence();                      // acquire: invalidate stale lines
}

// ---------------------------------------------------------------------------
// 5) Mega-tail (validated in r10): colstats -> pool -> gemm2 -> dgcn1(+BN3
//    stats) -> gemm3 -> dgcn2(+mean). 256 blocks x 256, LDS-light,
//    guaranteed co-resident; 5 barriers.
// ---------------------------------------------------------------------------
__global__ __launch_bounds__(256) void k_tail(
    const uint32* __restrict__ aggu, float* __restrict__ stats2,
    const float* __restrict__ g2, const float* __restrict__ bb2,
    float* __restrict__ pooled, const float* __restrict__ w2,
    float* __restrict__ z1, const float* __restrict__ scen,
    const float* __restrict__ fcol, const float* __restrict__ b2c,
    float* __restrict__ y1, float* __restrict__ stats3r,
    const float* __restrict__ g3, const float* __restrict__ bb3,
    const float* __restrict__ w3, float* __restrict__ z2,
    const float* __restrict__ b3c, float* __restrict__ out,
    float* __restrict__ meanr, int* __restrict__ ctrs)
{
    __shared__ float shA[256];
    __shared__ float sc[128], sf[128];
    __shared__ int flag;
    int t = threadIdx.x, blk = blockIdx.x;

    // ---- P0: column stats over bf16 agg -> stats2 ----
    {
        float s0 = 0.f, ss0 = 0.f, s1 = 0.f, ss1 = 0.f;
        for (int idx = blk * 256 + t; idx < N_NODES * 64; idx += 256 * 256) {
            uint32 u = aggu[idx];
            float a = blo(u), b = bhi(u);
            s0 += a; ss0 += a * a; s1 += b; ss1 += b * b;
        }
        shA[t] = s0; __syncthreads();
        if (t < 64) atomicAdd(&stats2[2 * t], shA[t] + shA[t + 64] + shA[t + 128] + shA[t + 192]);
        __syncthreads(); shA[t] = s1; __syncthreads();
        if (t < 64) atomicAdd(&stats2[2 * t + 1], shA[t] + shA[t + 64] + shA[t + 128] + shA[t + 192]);
        __syncthreads(); shA[t] = ss0; __syncthreads();
        if (t < 64) atomicAdd(&stats2[128 + 2 * t], shA[t] + shA[t + 64] + shA[t + 128] + shA[t + 192]);
        __syncthreads(); shA[t] = ss1; __syncthreads();
        if (t < 64) atomicAdd(&stats2[128 + 2 * t + 1], shA[t] + shA[t + 64] + shA[t + 128] + shA[t + 192]);
    }
    gbar(&ctrs[2], 256);

    // ---- P1: mean-pool of tanh(BN2(agg)) for graph g = blk ----
    {
        if (t < 128) {
            float mu  = stats2[t] * (1.0f / N_NODES);
            float var = stats2[128 + t] * (1.0f / N_NODES) - mu * mu;
            float rs  = rsqrtf(fmaxf(var, 0.f) + BN_EPS);
            float s   = rs * g2[t];
            sc[t] = s;
            sf[t] = bb2[t] - mu * s;
        }
        __syncthreads();
        int c = t & 63, grp = t >> 6;
        float c0s = sc[2 * c], c0f = sf[2 * c], c1s = sc[2 * c + 1], c1f = sf[2 * c + 1];
        const uint32* base = aggu + (size_t)blk * 256 * 64;
        float s0 = 0.f, s1 = 0.f;
        for (int r = grp * 64; r < grp * 64 + 64; r++) {
            uint32 u = base[r * 64 + c];
            s0 += ftanh(blo(u) * c0s + c0f);
            s1 += ftanh(bhi(u) * c1s + c1f);
        }
        shA[t] = s0; __syncthreads();
        if (t < 64) pooled[blk * 128 + 2 * t] = (shA[t] + shA[t + 64] + shA[t + 128] + shA[t + 192]) * (1.0f / 256.0f);
        __syncthreads(); shA[t] = s1; __syncthreads();
        if (t < 64) pooled[blk * 128 + 2 * t + 1] = (shA[t] + shA[t + 64] + shA[t + 128] + shA[t + 192]) * (1.0f / 256.0f);
    }
    gbar(&ctrs[3], 256);

    // ---- P2: z1 = pooled @ W2^T, row i = blk ----
    {
        if (t < 128) shA[t] = pooled[blk * 128 + t];
        __syncthreads();
        float acc = 0.f;
        const float* wr = w2 + t * 128;
        for (int k = 0; k < 128; k++) acc += shA[k] * wr[k];
        z1[blk * 256 + t] = acc;
    }
    gbar(&ctrs[4], 256);

    // ---- P3: y1 = dense GCN(z1) + BN3 stats (8-way replicas) ----
    {
        __syncthreads();
        float a = (scen[t * 256 + blk] >= THRE) ? 1.0f : 0.0f;
        if (t == blk) a += 1.0f;
        shA[t] = a * rsqrtf(fcol[t] + 1.0f);
        __syncthreads();
        float acc = 0.f;
        for (int k = 0; k < 256; k++) acc += shA[k] * z1[k * 256 + t];
        float v = rsqrtf(fcol[blk] + 1.0f) * acc + b2c[t];
        y1[blk * 256 + t] = v;
        float* s3 = stats3r + (blk & 7) * 512;
        atomicAdd(&s3[t], v);
        atomicAdd(&s3[256 + t], v * v);
    }
    gbar(&ctrs[5], 256);

    // ---- P4: z2 = tanh(BN3(y1)) @ W3^T, row i = blk ----
    {
        float s = 0.f, ss = 0.f;
        #pragma unroll
        for (int r = 0; r < 8; r++) {
            s  += stats3r[r * 512 + t];
            ss += stats3r[r * 512 + 256 + t];
        }
        float mu  = s * (1.0f / 256.0f);
        float var = ss * (1.0f / 256.0f) - mu * mu;
        float rs  = rsqrtf(fmaxf(var, 0.f) + BN_EPS);
        float scj = rs * g3[t];
        float sfj = bb3[t] - mu * scj;
        shA[t] = ftanh(y1[blk * 256 + t] * scj + sfj);
        __syncthreads();
        if (t < 128) {
            float acc = 0.f;
            const float* wr = w3 + t * 256;
            for (int k = 0; k < 256; k++) acc += shA[k] * wr[k];
            z2[blk * 128 + t] = acc;
        }
    }
    gbar(&ctrs[6], 256);

    // ---- P5: feat = tanh(dense GCN(z2)) -> out; mean via replicas ----
    {
        __syncthreads();
        float a = (scen[t * 256 + blk] >= THRE) ? 1.0f : 0.0f;
        if (t == blk) a += 1.0f;
        shA[t] = a * rsqrtf(fcol[t] + 1.0f);
        __syncthreads();
        if (t < 128) {
            float acc = 0.f;
            for (int k = 0; k < 256; k++) acc += shA[k] * z2[k * 128 + t];
            float v = ftanh(rsqrtf(fcol[blk] + 1.0f) * acc + b3c[t]);
            out[blk * 128 + t] = v;
            atomicAdd(&meanr[(blk & 7) * 128 + t], v);
        }
        __syncthreads();
        if (t == 0) {
            __threadfence();
            flag = (atomicAdd(&ctrs[7], 1) == 255) ? 1 : 0;
        }
        __syncthreads();
        if (flag) {
            __threadfence();
            if (t < 128) {
                float s = 0.f;
                #pragma unroll
                for (int r = 0; r < 8; r++) s += meanr[r * 128 + t];
                out[S_GRAPH * 128 + t] = s * (1.0f / 256.0f);
            }
        }
    }
}

// ---------------------------------------------------------------------------
extern "C" void kernel_launch(void* const* d_in, const int* in_sizes, int n_in,
                              void* d_out, int out_size, void* d_ws, size_t ws_size,
                              hipStream_t stream)
{
    const float* x        = (const float*)d_in[0];
    const float* edge_attr= (const float*)d_in[1];
    const float* scen     = (const float*)d_in[2];
    const float* wv       = (const float*)d_in[3];
    const float* bv       = (const float*)d_in[4];
    const float* wc       = (const float*)d_in[5];
    const float* bc       = (const float*)d_in[6];
    const float* w1       = (const float*)d_in[7];
    const float* b1c      = (const float*)d_in[8];
    const float* w2       = (const float*)d_in[9];
    const float* b2c      = (const float*)d_in[10];
    const float* w3       = (const float*)d_in[11];
    const float* b3c      = (const float*)d_in[12];
    const float* g1       = (const float*)d_in[13];
    const float* bb1      = (const float*)d_in[14];
    const float* g2       = (const float*)d_in[15];
    const float* bb2      = (const float*)d_in[16];
    const float* g3       = (const float*)d_in[17];
    const float* bb3      = (const float*)d_in[18];
    const int*  ei        = (const int*)d_in[20];
    const int*  nconp     = (const int*)d_in[22];
    const int*  src = ei;
    const int*  dst = ei + N_EDGES;

    float* wsf = (float*)d_ws;
    uint32*   h0u  = (uint32*)wsf;            // 16.7MB, dead after gemm1
    uint32*   aggu = (uint32*)wsf;            // alias
    uint32*   xwu  = (uint32*)(wsf + 4194304);// 16.7MB
    // zero-init block: pk32, stats, replicas, fcol, meanr, counters
    float* zb      = wsf + 8388608;
    uint32* pk32   = (uint32*)zb;             // 65536
    float* stats1  = zb + 65536;              // 512
    float* stats2  = stats1 + 512;            // 512
    float* stats3r = stats2 + 512;            // 4096
    float* fcol    = stats3r + 4096;          // 256
    float* meanr   = fcol + 256;              // 1024
    int*   ctrs    = (int*)(meanr + 1024);    // 8 counters
    const int ZN   = 65536 + 512 * 2 + 4096 + 256 + 1024 + 8;
    float* deg     = zb + ZN;                 // 65536 (dinv)
    int*   rowp    = (int*)(deg + 65536);     // 65536 (padded partial scan)
    int*   bsum    = rowp + 65536;            // 256
    int*   boff    = bsum + 256;              // 256
    uchar* rank    = (uchar*)(boff + 256);    // 524288 bytes
    int2*  epk     = (int2*)((float*)rank + 131072);  // up to 720896 int2
    uint32* w1bk   = (uint32*)(epk + 720896); // 8192 (32KB bf16 W1)
    float* pooled  = (float*)(w1bk + 8192);   // 32768
    float* z1      = pooled + 32768;          // 65536
    float* y1      = z1 + 65536;              // 65536
    float* z2      = y1 + 65536;              // 32768

    float* out = (float*)d_out;

    hipMemsetAsync(zb, 0, ZN * sizeof(float), stream);

    k_mlp_hist<<<2593, 256, 0, stream>>>(x, wv, bv, wc, bc, nconp, h0u, stats1,
                                         dst, edge_attr, pk32, rank,
                                         scen, fcol, w1, w1bk);
    k_scan<<<256, 256, 0, stream>>>(pk32, rowp, bsum, boff, deg, &ctrs[0]);
    k_gemm1f<<<3328, 256, 0, stream>>>(h0u, w1bk, g1, bb1, stats1, (ushort16*)xwu,
                                       src, dst, edge_attr, deg, rowp, boff,
                                       rank, pk32, epk);
    k_gather<<<N_NODES / 4, 256, 0, stream>>>(rowp, boff, pk32, epk, xwu, deg,
                                              (const float2*)b1c, aggu);
    k_tail<<<256, 256, 0, stream>>>(aggu, stats2, g2, bb2, pooled, w2, z1,
                                    scen, fcol, b2c, y1, stats3r, g3, bb3, w3,
                                    z2, b3c, out, meanr, ctrs);
}

// Round 12
// 275.238 us; speedup vs baseline: 2.5400x; 1.5319x over previous
//
#include <hip/hip_runtime.h>
#include <hip/hip_bf16.h>
#include <cstddef>

#define N_NODES 65536
#define N_EDGES 524288
#define S_GRAPH 256
#define BN_EPS 1e-5f
#define THRE 0.7f

typedef __hip_bfloat16 bf16;
typedef unsigned int uint32;
typedef unsigned char uchar;
typedef unsigned short ushort16;
typedef __attribute__((ext_vector_type(8))) short short8;
typedef __attribute__((ext_vector_type(4))) float f32x4;

__device__ __forceinline__ float blo(uint32 u) { return __uint_as_float(u << 16); }
__device__ __forceinline__ float bhi(uint32 u) { return __uint_as_float(u & 0xffff0000u); }

__device__ __forceinline__ uint32 packbf(float a, float b)
{
    bf16 ha = __float2bfloat16(a), hb = __float2bfloat16(b);
    unsigned short ua, ub;
    __builtin_memcpy(&ua, &ha, 2); __builtin_memcpy(&ub, &hb, 2);
    return (uint32)ua | ((uint32)ub << 16);
}

// fast tanh: 1 - 2/(e^{2x}+1); |err| ~1e-6, far below bf16 rounding (2^-9)
__device__ __forceinline__ float ftanh(float x)
{
    float e = __builtin_amdgcn_exp2f(x * 2.8853900817779268f);  // 2*log2(e)
    return 1.0f - 2.0f * __builtin_amdgcn_rcpf(e + 1.0f);
}

// ---------------------------------------------------------------------------
// 1) Fused front-end, 2593 blocks (latency-bound MLP overlaps transaction-
//    bound hist):
//    [0..511] node MLP -> bf16 h0 + BN1 stats; [512..2559] edge histogram
//    (packed 32-bit atomic: hi8=count, lo24=wsum 2^-18 fix; old hi8 = rank);
//    [2560..2591] dense col sums; [2592] W1 fp32->bf16 pack
// ---------------------------------------------------------------------------
__global__ __launch_bounds__(256) void k_mlp_hist(
    const float* __restrict__ x, const float* __restrict__ wv,
    const float* __restrict__ bv, const float* __restrict__ wc,
    const float* __restrict__ bc, const int* __restrict__ nconp,
    uint32* __restrict__ h0u, float* __restrict__ stats,
    const int* __restrict__ dst, const float* __restrict__ ew,
    uint32* __restrict__ pk32, uchar* __restrict__ rank,
    const float* __restrict__ scen, float* __restrict__ fcol,
    const float* __restrict__ w1f, uint32* __restrict__ w1bk)
{
    int t = threadIdx.x;
    int b = blockIdx.x;
    if (b >= 512) {
        if (b < 2560) {                           // ---- histogram path ----
            int e = (b - 512) * 256 + t;
            int d = dst[e];
            uint32 wfix = __float2uint_rn(ew[e] * 262144.0f);   // 2^18
            uint32 old = atomicAdd(&pk32[d], (1u << 24) | wfix);
            rank[e] = (uchar)(old >> 24);
        } else if (b < 2592) {                    // ---- dense col sums ----
            int r0 = (b - 2560) * 8;
            float s = 0.f;
            for (int r = r0; r < r0 + 8; r++)
                s += (scen[r * 256 + t] >= THRE) ? 1.0f : 0.0f;
            atomicAdd(&fcol[t], s);
        } else {                                  // ---- W1 -> bf16 pack ----
            const float4* w4 = (const float4*)w1f;
            uint2* wo = (uint2*)w1bk;
            #pragma unroll
            for (int it = 0; it < 16; it++) {
                int fi = it * 256 + t;            // 4096 float4
                float4 w = w4[fi];
                wo[fi] = make_uint2(packbf(w.x, w.y), packbf(w.z, w.w));
            }
        }
        return;
    }
    // ---- node MLP path: block handles 128 nodes ----
    __shared__ float xs[128 * 6];
    __shared__ float sh[256];
    int n0 = b * 128;
    if (t < 192) ((float4*)xs)[t] = ((const float4*)(x + (size_t)n0 * 6))[t];
    __syncthreads();

    int nc = *nconp;
    int lane = t & 63, wave = t >> 6;
    int j0 = 2 * lane;
    const float2* wv2 = (const float2*)wv;
    float2 wa0 = wv2[j0 * 3], wa1 = wv2[j0 * 3 + 1], wa2 = wv2[j0 * 3 + 2];
    float2 wb0 = wv2[j0 * 3 + 3], wb1 = wv2[j0 * 3 + 4], wb2 = wv2[j0 * 3 + 5];
    float wc0 = wc[j0], wc1 = wc[j0 + 1], bc0 = bc[j0], bc1 = bc[j0 + 1];
    float bv0 = bv[j0], bv1 = bv[j0 + 1];

    float s0 = 0.f, ss0 = 0.f, s1 = 0.f, ss1 = 0.f;
    #pragma unroll 4
    for (int m = 0; m < 32; m++) {
        int ln = wave * 32 + m;                   // local node, wave-uniform
        int n = n0 + ln;
        const float* xr = &xs[ln * 6];
        float a0, a1;
        if (n < nc) {
            float xv = xr[0];
            a0 = xv * wc0 + bc0; a1 = xv * wc1 + bc1;
        } else {
            float x0 = xr[0], x1 = xr[1], x2 = xr[2], x3 = xr[3], x4 = xr[4], x5 = xr[5];
            a0 = bv0 + x0 * wa0.x + x1 * wa0.y + x2 * wa1.x + x3 * wa1.y + x4 * wa2.x + x5 * wa2.y;
            a1 = bv1 + x0 * wb0.x + x1 * wb0.y + x2 * wb1.x + x3 * wb1.y + x4 * wb2.x + x5 * wb2.y;
        }
        uint32 pk = packbf(ftanh(a0), ftanh(a1));
        h0u[(size_t)n * 64 + lane] = pk;
        float v0 = blo(pk), v1 = bhi(pk);         // stats on rounded values
        s0 += v0; ss0 += v0 * v0; s1 += v1; ss1 += v1 * v1;
    }
    sh[t] = s0; __syncthreads();
    if (t < 64) atomicAdd(&stats[2 * t], sh[t] + sh[t + 64] + sh[t + 128] + sh[t + 192]);
    __syncthreads(); sh[t] = s1; __syncthreads();
    if (t < 64) atomicAdd(&stats[2 * t + 1], sh[t] + sh[t + 64] + sh[t + 128] + sh[t + 192]);
    __syncthreads(); sh[t] = ss0; __syncthreads();
    if (t < 64) atomicAdd(&stats[128 + 2 * t], sh[t] + sh[t + 64] + sh[t + 128] + sh[t + 192]);
    __syncthreads(); sh[t] = ss1; __syncthreads();
    if (t < 64) atomicAdd(&stats[128 + 2 * t + 1], sh[t] + sh[t + 64] + sh[t + 128] + sh[t + 192]);
}

// ---------------------------------------------------------------------------
// 2) Scan of PADDED counts ((cnt+3)&~3) -> rowp/bsum; dinv finalize; last-
//    finishing block performs the 256-entry top-level scan (boff).
// ---------------------------------------------------------------------------
__global__ void k_scan(const uint32* __restrict__ pk32, int* __restrict__ rowp,
                       int* __restrict__ bsum, int* __restrict__ boff,
                       float* __restrict__ deg, int* __restrict__ ctr)
{
    __shared__ int sh[256];
    __shared__ int flag;
    int b = blockIdx.x, t = threadIdx.x;
    int i = b * 256 + t;
    uint32 pv = pk32[i];
    int cnt = (int)(pv >> 24);
    int pcnt = (cnt + 3) & ~3;
    deg[i] = rsqrtf((float)(pv & 0xFFFFFFu) * 3.814697265625e-6f + 1.0f);  // 2^-18
    sh[t] = pcnt; __syncthreads();
    for (int o = 1; o < 256; o <<= 1) {
        int u = (t >= o) ? sh[t - o] : 0;
        __syncthreads();
        sh[t] += u;
        __syncthreads();
    }
    rowp[i] = sh[t] - pcnt;
    if (t == 255) atomicExch(&bsum[b], sh[255]);   // coherent-point write
    __syncthreads();
    if (t == 0) {
        __threadfence();
        flag = (atomicAdd(ctr, 1) == 255) ? 1 : 0;
    }
    __syncthreads();
    if (flag) {
        __threadfence();
        int v = bsum[t];
        sh[t] = v; __syncthreads();
        for (int o = 1; o < 256; o <<= 1) {
            int u = (t >= o) ? sh[t - o] : 0;
            __syncthreads();
            sh[t] += u;
            __syncthreads();
        }
        boff[t] = sh[t] - v;
    }
}

// ---------------------------------------------------------------------------
// 3) Fused: [0..1023]    xw = BN1(h0) @ W1^T via MFMA bf16
//           [1024..3071] fill real edges at rowp+boff+rank (atomic-free)
//           [3072..3327] fill pad slots [cnt,pcnt) with (n, w=0)
// ---------------------------------------------------------------------------
__global__ __launch_bounds__(256) void k_gemm1f(
    const uint32* __restrict__ h0u, const uint32* __restrict__ w1bk,
    const float* __restrict__ g1, const float* __restrict__ bb1,
    const float* __restrict__ stats, ushort16* __restrict__ xws,
    const int* __restrict__ src, const int* __restrict__ dst,
    const float* __restrict__ ew, const float* __restrict__ dinv,
    const int* __restrict__ rowp, const int* __restrict__ boff,
    const uchar* __restrict__ rank, const uint32* __restrict__ pk32,
    int2* __restrict__ epk)
{
    int t = threadIdx.x;
    int blk = blockIdx.x;
    if (blk >= 1024) {
        if (blk < 3072) {                         // ---- fill real edges ----
            int e = (blk - 1024) * 256 + t;
            int s = src[e], d = dst[e];
            int p = rowp[d] + boff[d >> 8] + (int)rank[e];
            float w = dinv[s] * ew[e] * dinv[d];
            epk[p] = make_int2(s, __float_as_int(w));
        } else {                                  // ---- fill pads ----
            int n = (blk - 3072) * 256 + t;
            int st = rowp[n] + boff[n >> 8];
            int cnt = (int)(pk32[n] >> 24);
            int pcnt = (cnt + 3) & ~3;
            for (int q = cnt; q < pcnt; q++) epk[st + q] = make_int2(n, 0);
        }
        return;
    }
    __shared__ short hn_s[64 * 136];    // bf16 bits, row-major, stride 136 (2-way max)
    __shared__ short w_s[128 * 136];
    __shared__ float sc[128], sf[128];
    int row0 = blk * 64;

    if (t < 128) {
        float mu  = stats[t] * (1.0f / N_NODES);
        float var = stats[128 + t] * (1.0f / N_NODES) - mu * mu;
        float rs  = rsqrtf(fmaxf(var, 0.f) + BN_EPS);
        float s   = rs * g1[t];
        sc[t] = s;
        sf[t] = bb1[t] - mu * s;
    }
    __syncthreads();

    const uint4* h4 = (const uint4*)(h0u + (size_t)row0 * 64);
    #pragma unroll
    for (int it = 0; it < 4; it++) {
        int slot = it * 256 + t;
        int r = slot >> 4, k0 = (slot & 15) * 8;
        uint4 u = h4[slot];
        uint32 ua[4] = {u.x, u.y, u.z, u.w};
        uint32 o[4];
        #pragma unroll
        for (int m = 0; m < 4; m++) {
            int k = k0 + 2 * m;
            o[m] = packbf(blo(ua[m]) * sc[k] + sf[k], bhi(ua[m]) * sc[k + 1] + sf[k + 1]);
        }
        *(uint4*)&hn_s[r * 136 + k0] = make_uint4(o[0], o[1], o[2], o[3]);
    }
    const uint4* wv4 = (const uint4*)w1bk;
    #pragma unroll
    for (int it = 0; it < 8; it++) {
        int s2 = it * 256 + t;              // 2048 uint4 (8 bf16 each)
        int c = s2 >> 4, k0 = (s2 & 15) * 8;
        *(uint4*)&w_s[c * 136 + k0] = wv4[s2];
    }
    __syncthreads();

    int lane = t & 63, wave = t >> 6;
    int m16 = lane & 15, kh = lane >> 4;
    int mbase = wave * 16;
    f32x4 acc[8] = {};
    #pragma unroll
    for (int ks = 0; ks < 4; ks++) {
        short8 a = *(const short8*)&hn_s[(mbase + m16) * 136 + ks * 32 + kh * 8];
        #pragma unroll
        for (int ct = 0; ct < 8; ct++) {
            short8 bfr = *(const short8*)&w_s[(ct * 16 + m16) * 136 + ks * 32 + kh * 8];
            acc[ct] = __builtin_amdgcn_mfma_f32_16x16x32_bf16(a, bfr, acc[ct], 0, 0, 0);
        }
    }
    #pragma unroll
    for (int ct = 0; ct < 8; ct++) {
        int col = ct * 16 + m16;
        #pragma unroll
        for (int r = 0; r < 4; r++) {
            int row = mbase + kh * 4 + r;
            bf16 hv = __float2bfloat16(acc[ct][r]);
            unsigned short us; __builtin_memcpy(&us, &hv, 2);
            xws[(size_t)(row0 + row) * 128 + col] = us;
        }
    }
}

// ---------------------------------------------------------------------------
// 4) CSR gather, remainder-free (rows padded to 4)
// ---------------------------------------------------------------------------
__global__ void k_gather(const int* __restrict__ rowp, const int* __restrict__ boff,
                         const uint32* __restrict__ pk32, const int2* __restrict__ epk,
                         const uint32* __restrict__ xwu, const float* __restrict__ dinv,
                         const float2* __restrict__ b1c2, uint32* __restrict__ aggu)
{
    int t = threadIdx.x;
    int lane = t & 63;
    int n = blockIdx.x * 4 + (t >> 6);
    int st = rowp[n] + boff[n >> 8];
    int pcnt = (((int)(pk32[n] >> 24)) + 3) & ~3;
    float di = dinv[n];
    float d2 = di * di;
    uint32 u0 = xwu[(size_t)n * 64 + lane];
    float2 bb = b1c2[lane];
    float ax = d2 * blo(u0) + bb.x;
    float ay = d2 * bhi(u0) + bb.y;
    int en = st + pcnt;
    for (int p = st; p < en; p += 4) {
        int2 q0 = epk[p], q1 = epk[p + 1], q2 = epk[p + 2], q3 = epk[p + 3];
        uint32 v0 = xwu[(size_t)q0.x * 64 + lane];
        uint32 v1 = xwu[(size_t)q1.x * 64 + lane];
        uint32 v2 = xwu[(size_t)q2.x * 64 + lane];
        uint32 v3 = xwu[(size_t)q3.x * 64 + lane];
        float w0 = __int_as_float(q0.y), w1 = __int_as_float(q1.y);
        float w2 = __int_as_float(q2.y), w3 = __int_as_float(q3.y);
        ax += w0 * blo(v0) + w1 * blo(v1) + w2 * blo(v2) + w3 * blo(v3);
        ay += w0 * bhi(v0) + w1 * bhi(v1) + w2 * bhi(v2) + w3 * bhi(v3);
    }
    aggu[(size_t)n * 64 + lane] = packbf(ax, ay);
}

// ---------------------------------------------------------------------------
// 5) Column stats over bf16-packed [N,128] -> 8-way replicated stats2r.
//    1024 blocks (16 waves/CU) for latency hiding; replica blk&7 keeps
//    per-address atomic contention at 128.
// ---------------------------------------------------------------------------
__global__ void k_colstats_bf(const uint32* __restrict__ m, float* __restrict__ stats2r)
{
    __shared__ float sh[256];
    int t = threadIdx.x, b = blockIdx.x;
    float s0 = 0.f, ss0 = 0.f, s1 = 0.f, ss1 = 0.f;
    for (int idx = b * 256 + t; idx < N_NODES * 64; idx += 1024 * 256) {
        uint32 u = m[idx];
        float a = blo(u), c = bhi(u);
        s0 += a; ss0 += a * a; s1 += c; ss1 += c * c;
    }
    float* st = stats2r + (b & 7) * 256;
    sh[t] = s0; __syncthreads();
    if (t < 64) atomicAdd(&st[2 * t], sh[t] + sh[t + 64] + sh[t + 128] + sh[t + 192]);
    __syncthreads(); sh[t] = s1; __syncthreads();
    if (t < 64) atomicAdd(&st[2 * t + 1], sh[t] + sh[t + 64] + sh[t + 128] + sh[t + 192]);
    __syncthreads(); sh[t] = ss0; __syncthreads();
    if (t < 64) atomicAdd(&st[128 + 2 * t], sh[t] + sh[t + 64] + sh[t + 128] + sh[t + 192]);
    __syncthreads(); sh[t] = ss1; __syncthreads();
    if (t < 64) atomicAdd(&st[128 + 2 * t + 1], sh[t] + sh[t + 64] + sh[t + 128] + sh[t + 192]);
}

// ---------------------------------------------------------------------------
// 6) Mean-pool of tanh(BN2(agg)) per graph; 512 threads (8 waves/CU)
// ---------------------------------------------------------------------------
__global__ __launch_bounds__(512) void k_pool(
    const uint32* __restrict__ aggu, const float* __restrict__ stats2r,
    const float* __restrict__ g2, const float* __restrict__ bb2,
    float* __restrict__ pooled)
{
    __shared__ float sc[128], sf[128], sh[512];
    int t = threadIdx.x, g = blockIdx.x;
    if (t < 128) {
        float su = 0.f, sq = 0.f;
        #pragma unroll
        for (int r = 0; r < 8; r++) {
            su += stats2r[r * 256 + t];
            sq += stats2r[r * 256 + 128 + t];
        }
        float mu  = su * (1.0f / N_NODES);
        float var = sq * (1.0f / N_NODES) - mu * mu;
        float rs  = rsqrtf(fmaxf(var, 0.f) + BN_EPS);
        float s   = rs * g2[t];
        sc[t] = s;
        sf[t] = bb2[t] - mu * s;
    }
    __syncthreads();
    int c = t & 63, grp = t >> 6;                 // 8 groups x 32 rows
    float c0s = sc[2 * c], c0f = sf[2 * c], c1s = sc[2 * c + 1], c1f = sf[2 * c + 1];
    const uint32* base = aggu + (size_t)g * 256 * 64;
    float s0 = 0.f, s1 = 0.f;
    for (int r = grp * 32; r < grp * 32 + 32; r++) {
        uint32 u = base[r * 64 + c];
        s0 += ftanh(blo(u) * c0s + c0f);
        s1 += ftanh(bhi(u) * c1s + c1f);
    }
    sh[t] = s0; __syncthreads();
    if (t < 64) {
        float acc = 0.f;
        #pragma unroll
        for (int k = 0; k < 8; k++) acc += sh[t + 64 * k];
        pooled[g * 128 + 2 * t] = acc * (1.0f / 256.0f);
    }
    __syncthreads(); sh[t] = s1; __syncthreads();
    if (t < 64) {
        float acc = 0.f;
        #pragma unroll
        for (int k = 0; k < 8; k++) acc += sh[t + 64 * k];
        pooled[g * 128 + 2 * t + 1] = acc * (1.0f / 256.0f);
    }
}

// z1 = pooled @ W2^T : [256,128] x [256,128]^T -> [256,256]
__global__ void k_gemm2(const float* __restrict__ pooled, const float* __restrict__ w2,
                        float* __restrict__ z1)
{
    __shared__ float row[128];
    int i = blockIdx.x, t = threadIdx.x;
    if (t < 128) row[t] = pooled[i * 128 + t];
    __syncthreads();
    float acc = 0.f;
    const float* wr = w2 + t * 128;
    for (int k = 0; k < 128; k++) acc += row[k] * wr[k];
    z1[i * 256 + t] = acc;
}

// y1 + fused BN3 stats into 8-way replicated accumulators
__global__ void k_dgcn1(const float* __restrict__ scen, const float* __restrict__ fcol,
                        const float* __restrict__ z1, const float* __restrict__ b2c,
                        float* __restrict__ y1, float* __restrict__ stats3r)
{
    __shared__ float wk[256];
    int i = blockIdx.x, t = threadIdx.x;
    float a = (scen[t * 256 + i] >= THRE) ? 1.0f : 0.0f;
    if (t == i) a += 1.0f;
    wk[t] = a * rsqrtf(fcol[t] + 1.0f);
    __syncthreads();
    float acc = 0.f;
    for (int k = 0; k < 256; k++) acc += wk[k] * z1[k * 256 + t];
    float v = rsqrtf(fcol[i] + 1.0f) * acc + b2c[t];
    y1[i * 256 + t] = v;
    float* s3 = stats3r + (i & 7) * 512;
    atomicAdd(&s3[t], v);
    atomicAdd(&s3[256 + t], v * v);
}

// z2 = tanh(BN3(y1)) @ W3^T : BN3+tanh applied while staging the row
__global__ void k_gemm3(const float* __restrict__ y1, const float* __restrict__ stats3r,
                        const float* __restrict__ g3, const float* __restrict__ bb3,
                        const float* __restrict__ w3, float* __restrict__ z2)
{
    __shared__ float row[256];
    int i = blockIdx.x, t = threadIdx.x;   // 256 blocks x 128
    for (int c = t; c < 256; c += 128) {
        float s = 0.f, ss = 0.f;
        #pragma unroll
        for (int r = 0; r < 8; r++) {
            s  += stats3r[r * 512 + c];
            ss += stats3r[r * 512 + 256 + c];
        }
        float mu  = s * (1.0f / 256.0f);
        float var = ss * (1.0f / 256.0f) - mu * mu;
        float rs  = rsqrtf(fmaxf(var, 0.f) + BN_EPS);
        float scj = rs * g3[c];
        float sfj = bb3[c] - mu * scj;
        row[c] = ftanh(y1[i * 256 + c] * scj + sfj);
    }
    __syncthreads();
    float acc = 0.f;
    const float* wr = w3 + t * 256;
    for (int k = 0; k < 256; k++) acc += row[k] * wr[k];
    z2[i * 128 + t] = acc;
}

// feat = tanh(dense GCN(z2)) -> out rows; mean via 8-way replicas; last
// finishing block folds replicas into the out tail.
__global__ void k_dgcn2(const float* __restrict__ scen, const float* __restrict__ fcol,
                        const float* __restrict__ z2, const float* __restrict__ b3c,
                        float* __restrict__ out, float* __restrict__ meanr,
                        int* __restrict__ ctr)
{
    __shared__ float wk[256];
    __shared__ int flag;
    int i = blockIdx.x, t = threadIdx.x;   // 256 blocks x 128
    for (int k = t; k < 256; k += 128) {
        float a = (scen[k * 256 + i] >= THRE) ? 1.0f : 0.0f;
        if (k == i) a += 1.0f;
        wk[k] = a * rsqrtf(fcol[k] + 1.0f);
    }
    __syncthreads();
    float acc = 0.f;
    for (int k = 0; k < 256; k++) acc += wk[k] * z2[k * 128 + t];
    float v = ftanh(rsqrtf(fcol[i] + 1.0f) * acc + b3c[t]);
    out[i * 128 + t] = v;
    atomicAdd(&meanr[(i & 7) * 128 + t], v);
    __syncthreads();
    if (t == 0) {
        __threadfence();
        flag = (atomicAdd(ctr, 1) == 255) ? 1 : 0;
    }
    __syncthreads();
    if (flag) {
        __threadfence();
        float s = 0.f;
        #pragma unroll
        for (int r = 0; r < 8; r++) s += meanr[r * 128 + t];
        out[S_GRAPH * 128 + t] = s * (1.0f / 256.0f);
    }
}

// ---------------------------------------------------------------------------
extern "C" void kernel_launch(void* const* d_in, const int* in_sizes, int n_in,
                              void* d_out, int out_size, void* d_ws, size_t ws_size,
                              hipStream_t stream)
{
    const float* x        = (const float*)d_in[0];
    const float* edge_attr= (const float*)d_in[1];
    const float* scen     = (const float*)d_in[2];
    const float* wv       = (const float*)d_in[3];
    const float* bv       = (const float*)d_in[4];
    const float* wc       = (const float*)d_in[5];
    const float* bc       = (const float*)d_in[6];
    const float* w1       = (const float*)d_in[7];
    const float* b1c      = (const float*)d_in[8];
    const float* w2       = (const float*)d_in[9];
    const float* b2c      = (const float*)d_in[10];
    const float* w3       = (const float*)d_in[11];
    const float* b3c      = (const float*)d_in[12];
    const float* g1       = (const float*)d_in[13];
    const float* bb1      = (const float*)d_in[14];
    const float* g2       = (const float*)d_in[15];
    const float* bb2      = (const float*)d_in[16];
    const float* g3       = (const float*)d_in[17];
    const float* bb3      = (const float*)d_in[18];
    const int*  ei        = (const int*)d_in[20];
    const int*  nconp     = (const int*)d_in[22];
    const int*  src = ei;
    const int*  dst = ei + N_EDGES;

    float* wsf = (float*)d_ws;
    uint32*   h0u  = (uint32*)wsf;            // 16.7MB, dead after gemm1
    uint32*   aggu = (uint32*)wsf;            // alias
    uint32*   xwu  = (uint32*)(wsf + 4194304);// 16.7MB
    // zero-init block: pk32, stats, replicas, fcol, meanr, counters
    float* zb      = wsf + 8388608;
    uint32* pk32   = (uint32*)zb;             // 65536
    float* stats1  = zb + 65536;              // 512
    float* stats2r = stats1 + 512;            // 8*256 = 2048
    float* stats3r = stats2r + 2048;          // 8*512 = 4096
    float* fcol    = stats3r + 4096;          // 256
    float* meanr   = fcol + 256;              // 1024
    int*   ctrs    = (int*)(meanr + 1024);    // 8 counters
    const int ZN   = 65536 + 512 + 2048 + 4096 + 256 + 1024 + 8;
    float* deg     = zb + ZN;                 // 65536 (dinv)
    int*   rowp    = (int*)(deg + 65536);     // 65536 (padded partial scan)
    int*   bsum    = rowp + 65536;            // 256
    int*   boff    = bsum + 256;              // 256
    uchar* rank    = (uchar*)(boff + 256);    // 524288 bytes
    int2*  epk     = (int2*)((float*)rank + 131072);  // up to 720896 int2
    uint32* w1bk   = (uint32*)(epk + 720896); // 8192 (32KB bf16 W1)
    float* pooled  = (float*)(w1bk + 8192);   // 32768
    float* z1      = pooled + 32768;          // 65536
    float* y1      = z1 + 65536;              // 65536
    float* z2      = y1 + 65536;              // 32768

    float* out = (float*)d_out;

    hipMemsetAsync(zb, 0, ZN * sizeof(float), stream);

    k_mlp_hist<<<2593, 256, 0, stream>>>(x, wv, bv, wc, bc, nconp, h0u, stats1,
                                         dst, edge_attr, pk32, rank,
                                         scen, fcol, w1, w1bk);
    k_scan<<<256, 256, 0, stream>>>(pk32, rowp, bsum, boff, deg, &ctrs[0]);
    k_gemm1f<<<3328, 256, 0, stream>>>(h0u, w1bk, g1, bb1, stats1, (ushort16*)xwu,
                                       src, dst, edge_attr, deg, rowp, boff,
                                       rank, pk32, epk);
    k_gather<<<N_NODES / 4, 256, 0, stream>>>(rowp, boff, pk32, epk, xwu, deg,
                                              (const float2*)b1c, aggu);
    k_colstats_bf<<<1024, 256, 0, stream>>>(aggu, stats2r);
    k_pool<<<S_GRAPH, 512, 0, stream>>>(aggu, stats2r, g2, bb2, pooled);
    k_gemm2<<<256, 256, 0, stream>>>(pooled, w2, z1);
    k_dgcn1<<<256, 256, 0, stream>>>(scen, fcol, z1, b2c, y1, stats3r);
    k_gemm3<<<256, 128, 0, stream>>>(y1, stats3r, g3, bb3, w3, z2);
    k_dgcn2<<<256, 128, 0, stream>>>(scen, fcol, z2, b3c, out, meanr, &ctrs[1]);
}

// Round 13
// 272.092 us; speedup vs baseline: 2.5693x; 1.0116x over previous
//
#include <hip/hip_runtime.h>
#include <hip/hip_bf16.h>
#include <cstddef>

#define N_NODES 65536
#define N_EDGES 524288
#define S_GRAPH 256
#define BN_EPS 1e-5f
#define THRE 0.7f

typedef __hip_bfloat16 bf16;
typedef unsigned int uint32;
typedef unsigned char uchar;
typedef unsigned short ushort16;
typedef __attribute__((ext_vector_type(8))) short short8;
typedef __attribute__((ext_vector_type(4))) float f32x4;

__device__ __forceinline__ float blo(uint32 u) { return __uint_as_float(u << 16); }
__device__ __forceinline__ float bhi(uint32 u) { return __uint_as_float(u & 0xffff0000u); }

__device__ __forceinline__ uint32 packbf(float a, float b)
{
    bf16 ha = __float2bfloat16(a), hb = __float2bfloat16(b);
    unsigned short ua, ub;
    __builtin_memcpy(&ua, &ha, 2); __builtin_memcpy(&ub, &hb, 2);
    return (uint32)ua | ((uint32)ub << 16);
}

// fast tanh: 1 - 2/(e^{2x}+1); |err| ~1e-6, far below bf16 rounding (2^-9)
__device__ __forceinline__ float ftanh(float x)
{
    float e = __builtin_amdgcn_exp2f(x * 2.8853900817779268f);  // 2*log2(e)
    return 1.0f - 2.0f * __builtin_amdgcn_rcpf(e + 1.0f);
}

// ---------------------------------------------------------------------------
// 1) Fused front-end, 2593 blocks. HIST FIRST so the atomic-rate-bound path
//    saturates from t=0; light MLP/ddeg/pack blocks fill remaining slots:
//    [0..2047]    edge histogram: packed 32-bit atomic (hi8=count, lo24=
//                 wsum 2^-18 fix); returned hi8 = within-bucket rank (u8)
//    [2048..2559] node MLP -> bf16 h0 + BN1 stats (x staged in LDS)
//    [2560..2591] dense adjacency column sums (fcol)
//    [2592]       pack W1 fp32 -> bf16
// ---------------------------------------------------------------------------
__global__ __launch_bounds__(256) void k_mlp_hist(
    const float* __restrict__ x, const float* __restrict__ wv,
    const float* __restrict__ bv, const float* __restrict__ wc,
    const float* __restrict__ bc, const int* __restrict__ nconp,
    uint32* __restrict__ h0u, float* __restrict__ stats,
    const int* __restrict__ dst, const float* __restrict__ ew,
    uint32* __restrict__ pk32, uchar* __restrict__ rank,
    const float* __restrict__ scen, float* __restrict__ fcol,
    const float* __restrict__ w1f, uint32* __restrict__ w1bk)
{
    int t = threadIdx.x;
    int b = blockIdx.x;
    if (b < 2048) {                               // ---- histogram path ----
        int e = b * 256 + t;
        int d = dst[e];
        uint32 wfix = __float2uint_rn(ew[e] * 262144.0f);   // 2^18
        uint32 old = atomicAdd(&pk32[d], (1u << 24) | wfix);
        rank[e] = (uchar)(old >> 24);
        return;
    }
    if (b >= 2560) {
        if (b < 2592) {                           // ---- dense col sums ----
            int r0 = (b - 2560) * 8;
            float s = 0.f;
            for (int r = r0; r < r0 + 8; r++)
                s += (scen[r * 256 + t] >= THRE) ? 1.0f : 0.0f;
            atomicAdd(&fcol[t], s);
        } else {                                  // ---- W1 -> bf16 pack ----
            const float4* w4 = (const float4*)w1f;
            uint2* wo = (uint2*)w1bk;
            #pragma unroll
            for (int it = 0; it < 16; it++) {
                int fi = it * 256 + t;            // 4096 float4
                float4 w = w4[fi];
                wo[fi] = make_uint2(packbf(w.x, w.y), packbf(w.z, w.w));
            }
        }
        return;
    }
    // ---- node MLP path: block handles 128 nodes ----
    __shared__ float xs[128 * 6];
    __shared__ float sh[256];
    int n0 = (b - 2048) * 128;
    if (t < 192) ((float4*)xs)[t] = ((const float4*)(x + (size_t)n0 * 6))[t];
    __syncthreads();

    int nc = *nconp;
    int lane = t & 63, wave = t >> 6;
    int j0 = 2 * lane;
    const float2* wv2 = (const float2*)wv;
    float2 wa0 = wv2[j0 * 3], wa1 = wv2[j0 * 3 + 1], wa2 = wv2[j0 * 3 + 2];
    float2 wb0 = wv2[j0 * 3 + 3], wb1 = wv2[j0 * 3 + 4], wb2 = wv2[j0 * 3 + 5];
    float wc0 = wc[j0], wc1 = wc[j0 + 1], bc0 = bc[j0], bc1 = bc[j0 + 1];
    float bv0 = bv[j0], bv1 = bv[j0 + 1];

    float s0 = 0.f, ss0 = 0.f, s1 = 0.f, ss1 = 0.f;
    #pragma unroll 4
    for (int m = 0; m < 32; m++) {
        int ln = wave * 32 + m;                   // local node, wave-uniform
        int n = n0 + ln;
        const float* xr = &xs[ln * 6];
        float a0, a1;
        if (n < nc) {
            float xv = xr[0];
            a0 = xv * wc0 + bc0; a1 = xv * wc1 + bc1;
        } else {
            float x0 = xr[0], x1 = xr[1], x2 = xr[2], x3 = xr[3], x4 = xr[4], x5 = xr[5];
            a0 = bv0 + x0 * wa0.x + x1 * wa0.y + x2 * wa1.x + x3 * wa1.y + x4 * wa2.x + x5 * wa2.y;
            a1 = bv1 + x0 * wb0.x + x1 * wb0.y + x2 * wb1.x + x3 * wb1.y + x4 * wb2.x + x5 * wb2.y;
        }
        uint32 pk = packbf(ftanh(a0), ftanh(a1));
        h0u[(size_t)n * 64 + lane] = pk;
        float v0 = blo(pk), v1 = bhi(pk);         // stats on rounded values
        s0 += v0; ss0 += v0 * v0; s1 += v1; ss1 += v1 * v1;
    }
    sh[t] = s0; __syncthreads();
    if (t < 64) atomicAdd(&stats[2 * t], sh[t] + sh[t + 64] + sh[t + 128] + sh[t + 192]);
    __syncthreads(); sh[t] = s1; __syncthreads();
    if (t < 64) atomicAdd(&stats[2 * t + 1], sh[t] + sh[t + 64] + sh[t + 128] + sh[t + 192]);
    __syncthreads(); sh[t] = ss0; __syncthreads();
    if (t < 64) atomicAdd(&stats[128 + 2 * t], sh[t] + sh[t + 64] + sh[t + 128] + sh[t + 192]);
    __syncthreads(); sh[t] = ss1; __syncthreads();
    if (t < 64) atomicAdd(&stats[128 + 2 * t + 1], sh[t] + sh[t + 64] + sh[t + 128] + sh[t + 192]);
}

// ---------------------------------------------------------------------------
// 2) Scan of PADDED counts ((cnt+3)&~3) -> rowp/bsum; dinv finalize; last-
//    finishing block performs the 256-entry top-level scan (boff).
// ---------------------------------------------------------------------------
__global__ void k_scan(const uint32* __restrict__ pk32, int* __restrict__ rowp,
                       int* __restrict__ bsum, int* __restrict__ boff,
                       float* __restrict__ deg, int* __restrict__ ctr)
{
    __shared__ int sh[256];
    __shared__ int flag;
    int b = blockIdx.x, t = threadIdx.x;
    int i = b * 256 + t;
    uint32 pv = pk32[i];
    int cnt = (int)(pv >> 24);
    int pcnt = (cnt + 3) & ~3;
    deg[i] = rsqrtf((float)(pv & 0xFFFFFFu) * 3.814697265625e-6f + 1.0f);  // 2^-18
    sh[t] = pcnt; __syncthreads();
    for (int o = 1; o < 256; o <<= 1) {
        int u = (t >= o) ? sh[t - o] : 0;
        __syncthreads();
        sh[t] += u;
        __syncthreads();
    }
    rowp[i] = sh[t] - pcnt;
    if (t == 255) atomicExch(&bsum[b], sh[255]);   // coherent-point write
    __syncthreads();
    if (t == 0) {
        __threadfence();
        flag = (atomicAdd(ctr, 1) == 255) ? 1 : 0;
    }
    __syncthreads();
    if (flag) {
        __threadfence();
        int v = bsum[t];
        sh[t] = v; __syncthreads();
        for (int o = 1; o < 256; o <<= 1) {
            int u = (t >= o) ? sh[t - o] : 0;
            __syncthreads();
            sh[t] += u;
            __syncthreads();
        }
        boff[t] = sh[t] - v;
    }
}

// ---------------------------------------------------------------------------
// 3) Fused: [0..1023]    xw = BN1(h0) @ W1^T via MFMA bf16
//           [1024..3071] fill real edges at rowp+boff+rank (atomic-free)
//           [3072..3327] fill pad slots [cnt,pcnt) with (n, w=0)
// ---------------------------------------------------------------------------
__global__ __launch_bounds__(256) void k_gemm1f(
    const uint32* __restrict__ h0u, const uint32* __restrict__ w1bk,
    const float* __restrict__ g1, const float* __restrict__ bb1,
    const float* __restrict__ stats, ushort16* __restrict__ xws,
    const int* __restrict__ src, const int* __restrict__ dst,
    const float* __restrict__ ew, const float* __restrict__ dinv,
    const int* __restrict__ rowp, const int* __restrict__ boff,
    const uchar* __restrict__ rank, const uint32* __restrict__ pk32,
    int2* __restrict__ epk)
{
    int t = threadIdx.x;
    int blk = blockIdx.x;
    if (blk >= 1024) {
        if (blk < 3072) {                         // ---- fill real edges ----
            int e = (blk - 1024) * 256 + t;
            int s = src[e], d = dst[e];
            int p = rowp[d] + boff[d >> 8] + (int)rank[e];
            float w = dinv[s] * ew[e] * dinv[d];
            epk[p] = make_int2(s, __float_as_int(w));
        } else {                                  // ---- fill pads ----
            int n = (blk - 3072) * 256 + t;
            int st = rowp[n] + boff[n >> 8];
            int cnt = (int)(pk32[n] >> 24);
            int pcnt = (cnt + 3) & ~3;
            for (int q = cnt; q < pcnt; q++) epk[st + q] = make_int2(n, 0);
        }
        return;
    }
    __shared__ short hn_s[64 * 136];    // bf16 bits, row-major, stride 136 (2-way max)
    __shared__ short w_s[128 * 136];
    __shared__ float sc[128], sf[128];
    int row0 = blk * 64;

    if (t < 128) {
        float mu  = stats[t] * (1.0f / N_NODES);
        float var = stats[128 + t] * (1.0f / N_NODES) - mu * mu;
        float rs  = rsqrtf(fmaxf(var, 0.f) + BN_EPS);
        float s   = rs * g1[t];
        sc[t] = s;
        sf[t] = bb1[t] - mu * s;
    }
    __syncthreads();

    const uint4* h4 = (const uint4*)(h0u + (size_t)row0 * 64);
    #pragma unroll
    for (int it = 0; it < 4; it++) {
        int slot = it * 256 + t;
        int r = slot >> 4, k0 = (slot & 15) * 8;
        uint4 u = h4[slot];
        uint32 ua[4] = {u.x, u.y, u.z, u.w};
        uint32 o[4];
        #pragma unroll
        for (int m = 0; m < 4; m++) {
            int k = k0 + 2 * m;
            o[m] = packbf(blo(ua[m]) * sc[k] + sf[k], bhi(ua[m]) * sc[k + 1] + sf[k + 1]);
        }
        *(uint4*)&hn_s[r * 136 + k0] = make_uint4(o[0], o[1], o[2], o[3]);
    }
    const uint4* wv4 = (const uint4*)w1bk;
    #pragma unroll
    for (int it = 0; it < 8; it++) {
        int s2 = it * 256 + t;              // 2048 uint4 (8 bf16 each)
        int c = s2 >> 4, k0 = (s2 & 15) * 8;
        *(uint4*)&w_s[c * 136 + k0] = wv4[s2];
    }
    __syncthreads();

    int lane = t & 63, wave = t >> 6;
    int m16 = lane & 15, kh = lane >> 4;
    int mbase = wave * 16;
    f32x4 acc[8] = {};
    #pragma unroll
    for (int ks = 0; ks < 4; ks++) {
        short8 a = *(const short8*)&hn_s[(mbase + m16) * 136 + ks * 32 + kh * 8];
        #pragma unroll
        for (int ct = 0; ct < 8; ct++) {
            short8 bfr = *(const short8*)&w_s[(ct * 16 + m16) * 136 + ks * 32 + kh * 8];
            acc[ct] = __builtin_amdgcn_mfma_f32_16x16x32_bf16(a, bfr, acc[ct], 0, 0, 0);
        }
    }
    #pragma unroll
    for (int ct = 0; ct < 8; ct++) {
        int col = ct * 16 + m16;
        #pragma unroll
        for (int r = 0; r < 4; r++) {
            int row = mbase + kh * 4 + r;
            bf16 hv = __float2bfloat16(acc[ct][r]);
            unsigned short us; __builtin_memcpy(&us, &hv, 2);
            xws[(size_t)(row0 + row) * 128 + col] = us;
        }
    }
}

// ---------------------------------------------------------------------------
// 4) CSR gather, remainder-free (rows padded to 4)
// ---------------------------------------------------------------------------
__global__ void k_gather(const int* __restrict__ rowp, const int* __restrict__ boff,
                         const uint32* __restrict__ pk32, const int2* __restrict__ epk,
                         const uint32* __restrict__ xwu, const float* __restrict__ dinv,
                         const float2* __restrict__ b1c2, uint32* __restrict__ aggu)
{
    int t = threadIdx.x;
    int lane = t & 63;
    int n = blockIdx.x * 4 + (t >> 6);
    int st = rowp[n] + boff[n >> 8];
    int pcnt = (((int)(pk32[n] >> 24)) + 3) & ~3;
    float di = dinv[n];
    float d2 = di * di;
    uint32 u0 = xwu[(size_t)n * 64 + lane];
    float2 bb = b1c2[lane];
    float ax = d2 * blo(u0) + bb.x;
    float ay = d2 * bhi(u0) + bb.y;
    int en = st + pcnt;
    for (int p = st; p < en; p += 4) {
        int2 q0 = epk[p], q1 = epk[p + 1], q2 = epk[p + 2], q3 = epk[p + 3];
        uint32 v0 = xwu[(size_t)q0.x * 64 + lane];
        uint32 v1 = xwu[(size_t)q1.x * 64 + lane];
        uint32 v2 = xwu[(size_t)q2.x * 64 + lane];
        uint32 v3 = xwu[(size_t)q3.x * 64 + lane];
        float w0 = __int_as_float(q0.y), w1 = __int_as_float(q1.y);
        float w2 = __int_as_float(q2.y), w3 = __int_as_float(q3.y);
        ax += w0 * blo(v0) + w1 * blo(v1) + w2 * blo(v2) + w3 * blo(v3);
        ay += w0 * bhi(v0) + w1 * bhi(v1) + w2 * bhi(v2) + w3 * bhi(v3);
    }
    aggu[(size_t)n * 64 + lane] = packbf(ax, ay);
}

// ---------------------------------------------------------------------------
// 5) Column stats over bf16-packed [N,128] -> 8-way replicated stats2r.
//    1024 blocks (16 waves/CU) for latency hiding.
// ---------------------------------------------------------------------------
__global__ void k_colstats_bf(const uint32* __restrict__ m, float* __restrict__ stats2r)
{
    __shared__ float sh[256];
    int t = threadIdx.x, b = blockIdx.x;
    float s0 = 0.f, ss0 = 0.f, s1 = 0.f, ss1 = 0.f;
    for (int idx = b * 256 + t; idx < N_NODES * 64; idx += 1024 * 256) {
        uint32 u = m[idx];
        float a = blo(u), c = bhi(u);
        s0 += a; ss0 += a * a; s1 += c; ss1 += c * c;
    }
    float* st = stats2r + (b & 7) * 256;
    sh[t] = s0; __syncthreads();
    if (t < 64) atomicAdd(&st[2 * t], sh[t] + sh[t + 64] + sh[t + 128] + sh[t + 192]);
    __syncthreads(); sh[t] = s1; __syncthreads();
    if (t < 64) atomicAdd(&st[2 * t + 1], sh[t] + sh[t + 64] + sh[t + 128] + sh[t + 192]);
    __syncthreads(); sh[t] = ss0; __syncthreads();
    if (t < 64) atomicAdd(&st[128 + 2 * t], sh[t] + sh[t + 64] + sh[t + 128] + sh[t + 192]);
    __syncthreads(); sh[t] = ss1; __syncthreads();
    if (t < 64) atomicAdd(&st[128 + 2 * t + 1], sh[t] + sh[t + 64] + sh[t + 128] + sh[t + 192]);
}

// ---------------------------------------------------------------------------
// 6) Fused pool + gemm2: block g computes pooled row g (LDS only), then
//    z1 row g = pooled_g @ W2^T. Row-local — no cross-block dependency.
//    512 threads (8 waves/CU).
// ---------------------------------------------------------------------------
__global__ __launch_bounds__(512) void k_poolg2(
    const uint32* __restrict__ aggu, const float* __restrict__ stats2r,
    const float* __restrict__ g2, const float* __restrict__ bb2,
    const float* __restrict__ w2, float* __restrict__ z1)
{
    __shared__ float sc[128], sf[128], sh[512], prow[128];
    int t = threadIdx.x, g = blockIdx.x;
    if (t < 128) {
        float su = 0.f, sq = 0.f;
        #pragma unroll
        for (int r = 0; r < 8; r++) {
            su += stats2r[r * 256 + t];
            sq += stats2r[r * 256 + 128 + t];
        }
        float mu  = su * (1.0f / N_NODES);
        float var = sq * (1.0f / N_NODES) - mu * mu;
        float rs  = rsqrtf(fmaxf(var, 0.f) + BN_EPS);
        float s   = rs * g2[t];
        sc[t] = s;
        sf[t] = bb2[t] - mu * s;
    }
    __syncthreads();
    int c = t & 63, grp = t >> 6;                 // 8 groups x 32 rows
    float c0s = sc[2 * c], c0f = sf[2 * c], c1s = sc[2 * c + 1], c1f = sf[2 * c + 1];
    const uint32* base = aggu + (size_t)g * 256 * 64;
    float s0 = 0.f, s1 = 0.f;
    for (int r = grp * 32; r < grp * 32 + 32; r++) {
        uint32 u = base[r * 64 + c];
        s0 += ftanh(blo(u) * c0s + c0f);
        s1 += ftanh(bhi(u) * c1s + c1f);
    }
    sh[t] = s0; __syncthreads();
    if (t < 64) {
        float acc = 0.f;
        #pragma unroll
        for (int k = 0; k < 8; k++) acc += sh[t + 64 * k];
        prow[2 * t] = acc * (1.0f / 256.0f);
    }
    __syncthreads(); sh[t] = s1; __syncthreads();
    if (t < 64) {
        float acc = 0.f;
        #pragma unroll
        for (int k = 0; k < 8; k++) acc += sh[t + 64 * k];
        prow[2 * t + 1] = acc * (1.0f / 256.0f);
    }
    __syncthreads();
    // ---- gemm2: z1[g][t] = sum_k prow[k] * w2[t][k], t < 256 ----
    if (t < 256) {
        float acc = 0.f;
        const float* wr = w2 + t * 128;
        for (int k = 0; k < 128; k++) acc += prow[k] * wr[k];
        z1[g * 256 + t] = acc;
    }
}

// y1 + fused BN3 stats into 8-way replicated accumulators
__global__ void k_dgcn1(const float* __restrict__ scen, const float* __restrict__ fcol,
                        const float* __restrict__ z1, const float* __restrict__ b2c,
                        float* __restrict__ y1, float* __restrict__ stats3r)
{
    __shared__ float wk[256];
    int i = blockIdx.x, t = threadIdx.x;
    float a = (scen[t * 256 + i] >= THRE) ? 1.0f : 0.0f;
    if (t == i) a += 1.0f;
    wk[t] = a * rsqrtf(fcol[t] + 1.0f);
    __syncthreads();
    float acc = 0.f;
    for (int k = 0; k < 256; k++) acc += wk[k] * z1[k * 256 + t];
    float v = rsqrtf(fcol[i] + 1.0f) * acc + b2c[t];
    y1[i * 256 + t] = v;
    float* s3 = stats3r + (i & 7) * 512;
    atomicAdd(&s3[t], v);
    atomicAdd(&s3[256 + t], v * v);
}

// z2 = tanh(BN3(y1)) @ W3^T : BN3+tanh applied while staging the row
__global__ void k_gemm3(const float* __restrict__ y1, const float* __restrict__ stats3r,
                        const float* __restrict__ g3, const float* __restrict__ bb3,
                        const float* __restrict__ w3, float* __restrict__ z2)
{
    __shared__ float row[256];
    int i = blockIdx.x, t = threadIdx.x;   // 256 blocks x 128
    for (int c = t; c < 256; c += 128) {
        float s = 0.f, ss = 0.f;
        #pragma unroll
        for (int r = 0; r < 8; r++) {
            s  += stats3r[r * 512 + c];
            ss += stats3r[r * 512 + 256 + c];
        }
        float mu  = s * (1.0f / 256.0f);
        float var = ss * (1.0f / 256.0f) - mu * mu;
        float rs  = rsqrtf(fmaxf(var, 0.f) + BN_EPS);
        float scj = rs * g3[c];
        float sfj = bb3[c] - mu * scj;
        row[c] = ftanh(y1[i * 256 + c] * scj + sfj);
    }
    __syncthreads();
    float acc = 0.f;
    const float* wr = w3 + t * 256;
    for (int k = 0; k < 256; k++) acc += row[k] * wr[k];
    z2[i * 128 + t] = acc;
}

// feat = tanh(dense GCN(z2)) -> out rows; mean via 8-way replicas; last
// finishing block folds replicas into the out tail.
__global__ void k_dgcn2(const float* __restrict__ scen, const float* __restrict__ fcol,
                        const float* __restrict__ z2, const float* __restrict__ b3c,
                        float* __restrict__ out, float* __restrict__ meanr,
                        int* __restrict__ ctr)
{
    __shared__ float wk[256];
    __shared__ int flag;
    int i = blockIdx.x, t = threadIdx.x;   // 256 blocks x 128
    for (int k = t; k < 256; k += 128) {
        float a = (scen[k * 256 + i] >= THRE) ? 1.0f : 0.0f;
        if (k == i) a += 1.0f;
        wk[k] = a * rsqrtf(fcol[k] + 1.0f);
    }
    __syncthreads();
    float acc = 0.f;
    for (int k = 0; k < 256; k++) acc += wk[k] * z2[k * 128 + t];
    float v = ftanh(rsqrtf(fcol[i] + 1.0f) * acc + b3c[t]);
    out[i * 128 + t] = v;
    atomicAdd(&meanr[(i & 7) * 128 + t], v);
    __syncthreads();
    if (t == 0) {
        __threadfence();
        flag = (atomicAdd(ctr, 1) == 255) ? 1 : 0;
    }
    __syncthreads();
    if (flag) {
        __threadfence();
        float s = 0.f;
        #pragma unroll
        for (int r = 0; r < 8; r++) s += meanr[r * 128 + t];
        out[S_GRAPH * 128 + t] = s * (1.0f / 256.0f);
    }
}

// ---------------------------------------------------------------------------
extern "C" void kernel_launch(void* const* d_in, const int* in_sizes, int n_in,
                              void* d_out, int out_size, void* d_ws, size_t ws_size,
                              hipStream_t stream)
{
    const float* x        = (const float*)d_in[0];
    const float* edge_attr= (const float*)d_in[1];
    const float* scen     = (const float*)d_in[2];
    const float* wv       = (const float*)d_in[3];
    const float* bv       = (const float*)d_in[4];
    const float* wc       = (const float*)d_in[5];
    const float* bc       = (const float*)d_in[6];
    const float* w1       = (const float*)d_in[7];
    const float* b1c      = (const float*)d_in[8];
    const float* w2       = (const float*)d_in[9];
    const float* b2c      = (const float*)d_in[10];
    const float* w3       = (const float*)d_in[11];
    const float* b3c      = (const float*)d_in[12];
    const float* g1       = (const float*)d_in[13];
    const float* bb1      = (const float*)d_in[14];
    const float* g2       = (const float*)d_in[15];
    const float* bb2      = (const float*)d_in[16];
    const float* g3       = (const float*)d_in[17];
    const float* bb3      = (const float*)d_in[18];
    const int*  ei        = (const int*)d_in[20];
    const int*  nconp     = (const int*)d_in[22];
    const int*  src = ei;
    const int*  dst = ei + N_EDGES;

    float* wsf = (float*)d_ws;
    uint32*   h0u  = (uint32*)wsf;            // 16.7MB, dead after gemm1
    uint32*   aggu = (uint32*)wsf;            // alias
    uint32*   xwu  = (uint32*)(wsf + 4194304);// 16.7MB
    // zero-init block: pk32, stats, replicas, fcol, meanr, counters
    float* zb      = wsf + 8388608;
    uint32* pk32   = (uint32*)zb;             // 65536
    float* stats1  = zb + 65536;              // 512
    float* stats2r = stats1 + 512;            // 8*256 = 2048
    float* stats3r = stats2r + 2048;          // 8*512 = 4096
    float* fcol    = stats3r + 4096;          // 256
    float* meanr   = fcol + 256;              // 1024
    int*   ctrs    = (int*)(meanr + 1024);    // 8 counters
    const int ZN   = 65536 + 512 + 2048 + 4096 + 256 + 1024 + 8;
    float* deg     = zb + ZN;                 // 65536 (dinv)
    int*   rowp    = (int*)(deg + 65536);     // 65536 (padded partial scan)
    int*   bsum    = rowp + 65536;            // 256
    int*   boff    = bsum + 256;              // 256
    uchar* rank    = (uchar*)(boff + 256);    // 524288 bytes
    int2*  epk     = (int2*)((float*)rank + 131072);  // up to 720896 int2
    uint32* w1bk   = (uint32*)(epk + 720896); // 8192 (32KB bf16 W1)
    float* z1      = (float*)(w1bk + 8192);   // 65536
    float* y1      = z1 + 65536;              // 65536
    float* z2      = y1 + 65536;              // 32768

    float* out = (float*)d_out;

    hipMemsetAsync(zb, 0, ZN * sizeof(float), stream);

    k_mlp_hist<<<2593, 256, 0, stream>>>(x, wv, bv, wc, bc, nconp, h0u, stats1,
                                         dst, edge_attr, pk32, rank,
                                         scen, fcol, w1, w1bk);
    k_scan<<<256, 256, 0, stream>>>(pk32, rowp, bsum, boff, deg, &ctrs[0]);
    k_gemm1f<<<3328, 256, 0, stream>>>(h0u, w1bk, g1, bb1, stats1, (ushort16*)xwu,
                                       src, dst, edge_attr, deg, rowp, boff,
                                       rank, pk32, epk);
    k_gather<<<N_NODES / 4, 256, 0, stream>>>(rowp, boff, pk32, epk, xwu, deg,
                                              (const float2*)b1c, aggu);
    k_colstats_bf<<<1024, 256, 0, stream>>>(aggu, stats2r);
    k_poolg2<<<S_GRAPH, 512, 0, stream>>>(aggu, stats2r, g2, bb2, w2, z1);
    k_dgcn1<<<256, 256, 0, stream>>>(scen, fcol, z1, b2c, y1, stats3r);
    k_gemm3<<<256, 128, 0, stream>>>(y1, stats3r, g3, bb3, w3, z2);
    k_dgcn2<<<256, 128, 0, stream>>>(scen, fcol, z2, b3c, out, meanr, &ctrs[1]);
}